// Round 1
// baseline (538.897 us; speedup 1.0000x reference)
//
#include <hip/hip_runtime.h>

typedef __bf16 bf16_t;
typedef __bf16 bf16x4 __attribute__((ext_vector_type(4)));
typedef __bf16 bf16x8 __attribute__((ext_vector_type(8)));
typedef float f32x4 __attribute__((ext_vector_type(4)));
typedef unsigned short u16;
typedef unsigned short u16x4 __attribute__((ext_vector_type(4)));
typedef unsigned int u32;
typedef unsigned int u32x4 __attribute__((ext_vector_type(4)));

#define B_ 4
#define N_ 64
#define P_ 256
#define C_ 384
#define H_ 6
#define D_ 64
#define M_TOTAL (B_*N_*P_)   // 65536 rows
#define NQKV (3*C_)          // 1152
#define ATTN_SMEM_BYTES 106496

__device__ __forceinline__ u16 f2b(float f){ return __builtin_bit_cast(u16, (bf16_t)f); }
__device__ __forceinline__ bf16_t b2bf(u16 u){ return __builtin_bit_cast(bf16_t, u); }
__device__ __forceinline__ u32 packsplit(float s){
    bf16_t hi = (bf16_t)s;
    bf16_t lo = (bf16_t)(s - (float)hi);
    return (u32)__builtin_bit_cast(u16, hi) | ((u32)__builtin_bit_cast(u16, lo) << 16);
}
__device__ __forceinline__ f32x4 mfma_bf16(bf16x8 a, bf16x8 b, f32x4 c){
    return __builtin_amdgcn_mfma_f32_16x16x32_bf16(a, b, c, 0, 0, 0);
}

// ---------------------------------------------------------------------------
// Kernel 0: transpose + bf16-split the weights once.
//  wTh/wTl: w_qkv^T as [n][k] hi/lo bf16 planes (1152 x 384)
//  wPt    : w_proj^T as [n][k] hi-only bf16     (384 x 384)
// ---------------------------------------------------------------------------
__global__ __launch_bounds__(256) void prep_w(
    const float* __restrict__ wqkv, const float* __restrict__ wproj,
    u16* __restrict__ wTh, u16* __restrict__ wTl, u16* __restrict__ wPt)
{
    int i = blockIdx.x * 256 + threadIdx.x;
    if (i < C_ * NQKV) {
        int k = i / NQKV, n = i % NQKV;
        float v = wqkv[i];
        bf16_t h = (bf16_t)v;
        bf16_t l = (bf16_t)(v - (float)h);
        wTh[(size_t)n * C_ + k] = __builtin_bit_cast(u16, h);
        wTl[(size_t)n * C_ + k] = __builtin_bit_cast(u16, l);
    }
    int j = i - C_ * NQKV;
    if (j >= 0 && j < C_ * C_) {
        int k = j / C_, n = j % C_;
        wPt[(size_t)n * C_ + k] = f2b(wproj[j]);
    }
}

// ---------------------------------------------------------------------------
// Kernel 1: QKV GEMM, split-bf16 (3-MFMA) for near-fp32 accuracy.
//  X (65536x384 f32) @ Wqkv (384x1152) -> qkv packed (hi,lo) u32 pairs.
//  128x128 tile, BK=32, 4 waves (2x2), 64x64 per wave.
// ---------------------------------------------------------------------------
__global__ __launch_bounds__(256, 2) void qkv_kernel(
    const float* __restrict__ x, const u16* __restrict__ wTh,
    const u16* __restrict__ wTl, u32* __restrict__ qkv)
{
    __shared__ alignas(16) u16 Ah[128*32];
    __shared__ alignas(16) u16 Al[128*32];
    __shared__ alignas(16) u16 Bh[128*32];
    __shared__ alignas(16) u16 Bl[128*32];

    const int tid = threadIdx.x;
    const int lane = tid & 63, wid = tid >> 6;
    const int wr = wid >> 1, wc = wid & 1;
    const int g = lane >> 4, r16 = lane & 15;
    const int m0 = blockIdx.x * 128;
    const int n0 = blockIdx.y * 128;

    f32x4 acc[4][4];
    for (int i = 0; i < 4; i++) for (int j = 0; j < 4; j++) acc[i][j] = f32x4{0.f,0.f,0.f,0.f};

    for (int kt = 0; kt < C_; kt += 32) {
        // stage A: x tile 128x32, split into hi/lo, 16B-block swizzle bg^= (row>>1)&3
        for (int r = 0; r < 4; ++r) {
            int i = tid + 256*r;            // 0..1023 quads
            int mm = i >> 3;                // row 0..127
            int kk = (i & 7) << 2;          // col 0,4,..,28
            f32x4 v = *(const f32x4*)&x[(size_t)(m0+mm)*C_ + kt + kk];
            u16 hs[4], ls[4];
            for (int jj = 0; jj < 4; jj++) {
                bf16_t h = (bf16_t)v[jj];
                hs[jj] = __builtin_bit_cast(u16, h);
                ls[jj] = f2b(v[jj] - (float)h);
            }
            int e = mm*32 + (((kk>>3) ^ ((mm>>1)&3))<<3) + (kk&7);
            *(u16x4*)&Ah[e] = u16x4{hs[0],hs[1],hs[2],hs[3]};
            *(u16x4*)&Al[e] = u16x4{ls[0],ls[1],ls[2],ls[3]};
        }
        // stage B: pre-transposed wTh/wTl rows are k-contiguous -> vector copies
        for (int r = 0; r < 4; ++r) {
            int i = tid + 256*r;
            int nn = i >> 3;                // n 0..127
            int kk = (i & 7) << 2;
            u16x4 hv = *(const u16x4*)&wTh[(size_t)(n0+nn)*C_ + kt + kk];
            u16x4 lv = *(const u16x4*)&wTl[(size_t)(n0+nn)*C_ + kt + kk];
            int e = nn*32 + (((kk>>3) ^ ((nn>>1)&3))<<3) + (kk&7);
            *(u16x4*)&Bh[e] = hv;
            *(u16x4*)&Bl[e] = lv;
        }
        __syncthreads();

        bf16x8 ah[4], al[4], bh[4], bl[4];
        for (int i = 0; i < 4; i++) {
            int row = wr*64 + i*16 + r16;
            int e = row*32 + ((g ^ ((row>>1)&3))<<3);
            ah[i] = *(const bf16x8*)&Ah[e];
            al[i] = *(const bf16x8*)&Al[e];
        }
        for (int j = 0; j < 4; j++) {
            int n = wc*64 + j*16 + r16;
            int e = n*32 + ((g ^ ((n>>1)&3))<<3);
            bh[j] = *(const bf16x8*)&Bh[e];
            bl[j] = *(const bf16x8*)&Bl[e];
        }
        for (int i = 0; i < 4; i++) for (int j = 0; j < 4; j++) {
            acc[i][j] = mfma_bf16(ah[i], bh[j], acc[i][j]);
            acc[i][j] = mfma_bf16(ah[i], bl[j], acc[i][j]);
            acc[i][j] = mfma_bf16(al[i], bh[j], acc[i][j]);
        }
        __syncthreads();
    }
    // epilogue: C layout col=lane&15, row=(lane>>4)*4+reg. Re-split to (hi,lo) pair.
    for (int i = 0; i < 4; i++) for (int j = 0; j < 4; j++) for (int rr = 0; rr < 4; rr++) {
        size_t row = m0 + wr*64 + i*16 + g*4 + rr;
        int col = n0 + wc*64 + j*16 + r16;
        qkv[row*NQKV + col] = packsplit(acc[i][j][rr]);
    }
}

// ---------------------------------------------------------------------------
// Kernel 2: per-(b,n,h) attention. Block = 512 thr (8 waves), each wave owns
// 16 q-rows (block covers 128 rows; grid.x=2 halves). Full 256-col score rows
// live in registers -> exact softmax without online rescaling.
// QK^T uses split-bf16 (3 MFMA), PV plain bf16.
// ---------------------------------------------------------------------------
__global__ __launch_bounds__(512, 2) void attn_kernel(
    const u32* __restrict__ qkv, u16* __restrict__ attn)
{
    extern __shared__ char smemraw[];
    u16* Kh = (u16*)smemraw;          // 256*64
    u16* Kl = Kh + 256*64;            // 256*64
    u16* Vt = Kl + 256*64;            // 64*256 (transposed, hi only)
    u16* Pb = Vt + 64*256;            // 8 waves * 16*32

    const int tid = threadIdx.x;
    const int lane = tid & 63, wid = tid >> 6;
    const int g = lane >> 4, r16 = lane & 15;
    const int rowhalf = blockIdx.x;   // 0..1
    const int h = blockIdx.y;         // 0..5
    const int bn = blockIdx.z;        // 0..255
    const size_t row0 = (size_t)bn * P_;

    // ---- stage K (hi/lo, swizzled) and V^T (hi, swizzled) ----
    for (int r = 0; r < 8; ++r) {
        int i = tid + 512*r;          // 0..4095 quad-slots
        int q = i >> 4;               // 0..255
        int d4 = (i & 15) << 2;       // 0,4,..,60
        u32x4 kv = *(const u32x4*)&qkv[(row0 + q)*NQKV + C_ + h*D_ + d4];
        u32x4 vv = *(const u32x4*)&qkv[(row0 + q)*NQKV + 2*C_ + h*D_ + d4];
        {
            int e = q*64 + (((d4>>3) ^ (q&7))<<3) + (d4&7);
            *(u16x4*)&Kh[e] = u16x4{(u16)kv[0],(u16)kv[1],(u16)kv[2],(u16)kv[3]};
            *(u16x4*)&Kl[e] = u16x4{(u16)(kv[0]>>16),(u16)(kv[1]>>16),(u16)(kv[2]>>16),(u16)(kv[3]>>16)};
        }
        for (int jj = 0; jj < 4; jj++) {
            int d = d4 + jj;
            int e = d*256 + ((((q>>3) ^ (d&7)))<<3) + (q&7);
            Vt[e] = (u16)vv[jj];
        }
    }

    // ---- Q fragments straight from global (split) ----
    const int prow = rowhalf*128 + wid*16 + r16;
    const u32* qr = &qkv[(row0 + prow)*NQKV + h*D_];
    bf16x8 aqh[2], aql[2];
    for (int s = 0; s < 2; s++) {
        u32x4 u0 = *(const u32x4*)&qr[32*s + 8*g];
        u32x4 u1 = *(const u32x4*)&qr[32*s + 8*g + 4];
        u32 us[8] = {u0[0],u0[1],u0[2],u0[3],u1[0],u1[1],u1[2],u1[3]};
        for (int jj = 0; jj < 8; jj++) {
            aqh[s][jj] = b2bf((u16)us[jj]);
            aql[s][jj] = b2bf((u16)(us[jj] >> 16));
        }
    }
    __syncthreads();

    // ---- S = Q K^T (split, 3 MFMA per k-step) ----
    f32x4 sa[16];
    for (int j = 0; j < 16; j++) sa[j] = f32x4{0.f,0.f,0.f,0.f};
    for (int j = 0; j < 16; j++) {
        int q = j*16 + r16;
        for (int s = 0; s < 2; s++) {
            int e = q*64 + (((4*s + g) ^ (q&7))<<3);
            bf16x8 bh = *(const bf16x8*)&Kh[e];
            bf16x8 bl = *(const bf16x8*)&Kl[e];
            sa[j] = mfma_bf16(aqh[s], bh, sa[j]);
            sa[j] = mfma_bf16(aqh[s], bl, sa[j]);
            sa[j] = mfma_bf16(aql[s], bh, sa[j]);
        }
    }

    // ---- softmax over 256 cols; row r = 4g+rr, cols spread over 16 lanes ----
    float mrow[4] = {-1e30f,-1e30f,-1e30f,-1e30f};
    for (int j = 0; j < 16; j++) for (int rr = 0; rr < 4; rr++)
        mrow[rr] = fmaxf(mrow[rr], sa[j][rr]);
    for (int mask = 1; mask < 16; mask <<= 1)
        for (int rr = 0; rr < 4; rr++)
            mrow[rr] = fmaxf(mrow[rr], __shfl_xor(mrow[rr], mask, 64));
    float ssum[4] = {0.f,0.f,0.f,0.f};
    for (int j = 0; j < 16; j++) for (int rr = 0; rr < 4; rr++) {
        float p = __expf((sa[j][rr] - mrow[rr]) * 64.0f);   // reference scale = D
        sa[j][rr] = p;
        ssum[rr] += p;
    }
    for (int mask = 1; mask < 16; mask <<= 1)
        for (int rr = 0; rr < 4; rr++)
            ssum[rr] += __shfl_xor(ssum[rr], mask, 64);
    float inv[4];
    for (int rr = 0; rr < 4; rr++) inv[rr] = 1.0f / ssum[rr];

    // ---- O = P V via per-wave LDS transpose buffer ----
    f32x4 oa[4];
    for (int nt = 0; nt < 4; nt++) oa[nt] = f32x4{0.f,0.f,0.f,0.f};
    u16* myPb = Pb + wid*512;
    for (int t = 0; t < 8; t++) {
        for (int tt = 0; tt < 2; tt++) {
            int j = 2*t + tt;
            for (int rr = 0; rr < 4; rr++)
                myPb[(4*g + rr)*32 + tt*16 + r16] = f2b(sa[j][rr] * inv[rr]);
        }
        __syncthreads();   // conservative: guarantees cross-lane LDS visibility
        bf16x8 ap = *(const bf16x8*)&myPb[r16*32 + 8*g];
        for (int nt = 0; nt < 4; nt++) {
            int d = nt*16 + r16;
            int q0 = t*32 + 8*g;
            int e = d*256 + ((((q0>>3) ^ (d&7)))<<3);
            bf16x8 bv = *(const bf16x8*)&Vt[e];
            oa[nt] = mfma_bf16(ap, bv, oa[nt]);
        }
        __syncthreads();
    }

    for (int nt = 0; nt < 4; nt++) for (int rr = 0; rr < 4; rr++) {
        int p = rowhalf*128 + wid*16 + 4*g + rr;
        int col = h*D_ + nt*16 + r16;
        attn[(row0 + p)*C_ + col] = f2b(oa[nt][rr]);
    }
}

// ---------------------------------------------------------------------------
// Kernel 3: output projection, plain bf16 MFMA. attn(65536x384 bf16) @
// w_proj(384x384) + bias -> f32 out. Same tiling as kernel 1 (no split).
// ---------------------------------------------------------------------------
__global__ __launch_bounds__(256, 2) void proj_kernel(
    const u16* __restrict__ attn, const u16* __restrict__ wPt,
    const float* __restrict__ bias, float* __restrict__ out)
{
    __shared__ alignas(16) u16 As[128*32];
    __shared__ alignas(16) u16 Bs[128*32];

    const int tid = threadIdx.x;
    const int lane = tid & 63, wid = tid >> 6;
    const int wr = wid >> 1, wc = wid & 1;
    const int g = lane >> 4, r16 = lane & 15;
    const int m0 = blockIdx.x * 128;
    const int n0 = blockIdx.y * 128;

    f32x4 acc[4][4];
    for (int i = 0; i < 4; i++) for (int j = 0; j < 4; j++) acc[i][j] = f32x4{0.f,0.f,0.f,0.f};

    for (int kt = 0; kt < C_; kt += 32) {
        for (int r = 0; r < 4; ++r) {
            int i = tid + 256*r;
            int mm = i >> 3;
            int kk = (i & 7) << 2;
            u16x4 v = *(const u16x4*)&attn[(size_t)(m0+mm)*C_ + kt + kk];
            int e = mm*32 + (((kk>>3) ^ ((mm>>1)&3))<<3) + (kk&7);
            *(u16x4*)&As[e] = v;
        }
        for (int r = 0; r < 4; ++r) {
            int i = tid + 256*r;
            int nn = i >> 3;
            int kk = (i & 7) << 2;
            u16x4 v = *(const u16x4*)&wPt[(size_t)(n0+nn)*C_ + kt + kk];
            int e = nn*32 + (((kk>>3) ^ ((nn>>1)&3))<<3) + (kk&7);
            *(u16x4*)&Bs[e] = v;
        }
        __syncthreads();

        bf16x8 a[4], b[4];
        for (int i = 0; i < 4; i++) {
            int row = wr*64 + i*16 + r16;
            a[i] = *(const bf16x8*)&As[row*32 + ((g ^ ((row>>1)&3))<<3)];
        }
        for (int j = 0; j < 4; j++) {
            int n = wc*64 + j*16 + r16;
            b[j] = *(const bf16x8*)&Bs[n*32 + ((g ^ ((n>>1)&3))<<3)];
        }
        for (int i = 0; i < 4; i++) for (int j = 0; j < 4; j++)
            acc[i][j] = mfma_bf16(a[i], b[j], acc[i][j]);
        __syncthreads();
    }

    for (int i = 0; i < 4; i++) for (int j = 0; j < 4; j++) for (int rr = 0; rr < 4; rr++) {
        size_t row = m0 + wr*64 + i*16 + g*4 + rr;
        int col = n0 + wc*64 + j*16 + r16;
        out[row*C_ + col] = acc[i][j][rr] + bias[col];
    }
}

// ---------------------------------------------------------------------------
extern "C" void kernel_launch(void* const* d_in, const int* in_sizes, int n_in,
                              void* d_out, int out_size, void* d_ws, size_t ws_size,
                              hipStream_t stream)
{
    const float* x      = (const float*)d_in[0];
    const float* w_qkv  = (const float*)d_in[1];
    const float* w_proj = (const float*)d_in[2];
    const float* b_proj = (const float*)d_in[3];
    float* out = (float*)d_out;

    char* ws = (char*)d_ws;
    u32* qkv  = (u32*)ws;                               // 65536*1152*4 B = 302 MB
    size_t off = (size_t)M_TOTAL * NQKV * sizeof(u32);
    u16* attn = (u16*)(ws + off); off += (size_t)M_TOTAL * C_ * sizeof(u16);   // 50 MB
    u16* wTh  = (u16*)(ws + off); off += (size_t)NQKV * C_ * sizeof(u16);
    u16* wTl  = (u16*)(ws + off); off += (size_t)NQKV * C_ * sizeof(u16);
    u16* wPt  = (u16*)(ws + off); off += (size_t)C_ * C_ * sizeof(u16);

    hipFuncSetAttribute((const void*)attn_kernel,
                        hipFuncAttributeMaxDynamicSharedMemorySize, ATTN_SMEM_BYTES);

    int prep_n = C_*NQKV + C_*C_;
    prep_w<<<dim3((prep_n + 255)/256), 256, 0, stream>>>(w_qkv, w_proj, wTh, wTl, wPt);
    qkv_kernel<<<dim3(M_TOTAL/128, NQKV/128), 256, 0, stream>>>(x, wTh, wTl, qkv);
    attn_kernel<<<dim3(2, H_, B_*N_), 512, ATTN_SMEM_BYTES, stream>>>(qkv, attn);
    proj_kernel<<<dim3(M_TOTAL/128, C_/128), 256, 0, stream>>>(attn, wPt, b_proj, out);
}

// Round 2
// 303.589 us; speedup vs baseline: 1.7751x; 1.7751x over previous
//
#include <hip/hip_runtime.h>

typedef __bf16 bf16_t;
typedef __bf16 bf16x8 __attribute__((ext_vector_type(8)));
typedef float f32x4 __attribute__((ext_vector_type(4)));
typedef unsigned short u16;
typedef unsigned short u16x4 __attribute__((ext_vector_type(4)));
typedef unsigned int u32;

#define B_ 4
#define N_ 64
#define P_ 256
#define C_ 384
#define H_ 6
#define D_ 64
#define M_TOTAL 65536
#define NQKV 1152
#define KSTEPS 12                     // 384/32
#define NFRAG 12                     // 192/16 (Q|K|V cols per head)
#define WF_HSTRIDE (KSTEPS*NFRAG*512) // u16 per head in frag-packed weights
#define FUSED_LDS 147456

__device__ __forceinline__ u16 f2b(float f){ return __builtin_bit_cast(u16, (bf16_t)f); }
__device__ __forceinline__ f32x4 mfma(bf16x8 a, bf16x8 b, f32x4 c){
    return __builtin_amdgcn_mfma_f32_16x16x32_bf16(a, b, c, 0, 0, 0);
}

// ---------------------------------------------------------------------------
// prep: (a) per-head fragment-packed split weights Wfh/Wfl[h][ks][nf][lane][8]
//       (b) w_proj^T bf16 for the proj GEMM
// ---------------------------------------------------------------------------
__global__ __launch_bounds__(256) void prep_w(
    const float* __restrict__ wqkv, const float* __restrict__ wproj,
    u16* __restrict__ Wfh, u16* __restrict__ Wfl, u16* __restrict__ wPt)
{
    int i = blockIdx.x * 256 + threadIdx.x;
    const int NSLOT = H_ * KSTEPS * NFRAG * 64;   // 55296
    if (i < NSLOT) {
        int lane = i & 63;
        int frag = i >> 6;
        int nf = frag % NFRAG;
        int ks = (frag / NFRAG) % KSTEPS;
        int h  = frag / (NFRAG * KSTEPS);
        int part = nf >> 2;                        // 0=Q 1=K 2=V
        int nh   = (nf & 3) * 16 + (lane & 15);    // 0..63 within head
        int col  = part * C_ + h * 64 + nh;        // col in w_qkv
        int k0   = ks * 32 + (lane >> 4) * 8;
        #pragma unroll
        for (int e = 0; e < 8; ++e) {
            float w = wqkv[(size_t)(k0 + e) * NQKV + col];
            bf16_t hi = (bf16_t)w;
            Wfh[(size_t)i * 8 + e] = __builtin_bit_cast(u16, hi);
            Wfl[(size_t)i * 8 + e] = f2b(w - (float)hi);
        }
    }
    int j = i - NSLOT;
    if (j >= 0 && j < C_ * C_) {
        int k = j / C_, n = j % C_;
        wPt[(size_t)n * C_ + k] = f2b(wproj[j]);
    }
}

// ---------------------------------------------------------------------------
// fused per-(h, b*n) kernel: QKV projection (split bf16) + attention.
// 512 threads = 8 waves; wave owns 32 q-rows. One __syncthreads total.
// ---------------------------------------------------------------------------
__global__ __launch_bounds__(512, 2) void fused_attn(
    const float* __restrict__ x, const u16* __restrict__ Wfh,
    const u16* __restrict__ Wfl, u16* __restrict__ attn)
{
    extern __shared__ u16 sm[];
    u16* Kh = sm;              // [256][64] swizzled
    u16* Kl = sm + 16384;
    u16* Vt = sm + 32768;      // [64][256] swizzled
    u16* Qb = sm + 49152;      // 8 waves x 2048 (Q bounce; reused as P bounce)

    const int tid  = threadIdx.x;
    const int lane = tid & 63, wid = tid >> 6;
    const int g = lane >> 4, r16 = lane & 15;
    const int h  = blockIdx.x;
    const int bn = blockIdx.y;
    const size_t row0 = (size_t)bn * P_;
    const int m0w = wid * 32;

    // ---------------- phase 1: [Q|K|V] = X_slab @ W3head, split bf16 -------
    f32x4 acc[2][12];
    #pragma unroll
    for (int mf = 0; mf < 2; ++mf)
        #pragma unroll
        for (int nf = 0; nf < 12; ++nf) acc[mf][nf] = f32x4{0.f,0.f,0.f,0.f};

    const float* xr0 = x + (row0 + m0w + r16) * C_;
    const float* xr1 = xr0 + 16 * C_;
    const u16* wh = Wfh + (size_t)h * WF_HSTRIDE + lane * 8;
    const u16* wl = Wfl + (size_t)h * WF_HSTRIDE + lane * 8;

    for (int ks = 0; ks < KSTEPS; ++ks) {
        bf16x8 ah[2], al[2];
        {
            const float* xp0 = xr0 + ks * 32 + 8 * g;
            const float* xp1 = xr1 + ks * 32 + 8 * g;
            f32x4 a0 = *(const f32x4*)xp0, b0 = *(const f32x4*)(xp0 + 4);
            f32x4 a1 = *(const f32x4*)xp1, b1 = *(const f32x4*)(xp1 + 4);
            #pragma unroll
            for (int e = 0; e < 4; ++e) {
                bf16_t h0 = (bf16_t)a0[e], h1 = (bf16_t)b0[e];
                ah[0][e] = h0;   al[0][e]   = (bf16_t)(a0[e] - (float)h0);
                ah[0][4+e] = h1; al[0][4+e] = (bf16_t)(b0[e] - (float)h1);
                bf16_t h2 = (bf16_t)a1[e], h3 = (bf16_t)b1[e];
                ah[1][e] = h2;   al[1][e]   = (bf16_t)(a1[e] - (float)h2);
                ah[1][4+e] = h3; al[1][4+e] = (bf16_t)(b1[e] - (float)h3);
            }
        }
        const u16* whk = wh + ks * (NFRAG * 512);
        const u16* wlk = wl + ks * (NFRAG * 512);
        #pragma unroll
        for (int nf = 0; nf < 12; ++nf) {
            bf16x8 bh = *(const bf16x8*)(whk + nf * 512);
            acc[0][nf] = mfma(ah[0], bh, acc[0][nf]);
            acc[1][nf] = mfma(ah[1], bh, acc[1][nf]);
            if (nf < 8) {   // Q,K need split accuracy; V plain
                bf16x8 bl = *(const bf16x8*)(wlk + nf * 512);
                acc[0][nf] = mfma(ah[0], bl, acc[0][nf]);
                acc[1][nf] = mfma(ah[1], bl, acc[1][nf]);
                acc[0][nf] = mfma(al[0], bh, acc[0][nf]);
                acc[1][nf] = mfma(al[1], bh, acc[1][nf]);
            }
        }
    }

    // ---- epilogue: K -> Kh/Kl (split), V -> Vt (transposed), swizzled ----
    #pragma unroll
    for (int mf = 0; mf < 2; ++mf)
    #pragma unroll
    for (int f = 0; f < 4; ++f)
    #pragma unroll
    for (int rr = 0; rr < 4; ++rr) {
        int q = m0w + mf * 16 + 4 * g + rr;
        int d = f * 16 + r16;
        int ek = q * 64 + (((d >> 3) ^ (q & 7)) << 3) + (d & 7);
        float kv = acc[mf][4 + f][rr];
        bf16_t khi = (bf16_t)kv;
        Kh[ek] = __builtin_bit_cast(u16, khi);
        Kl[ek] = f2b(kv - (float)khi);
        Vt[d * 256 + (((q >> 3) ^ (d & 7)) << 3) + (q & 7)] = f2b(acc[mf][8 + f][rr]);
    }

    // ---- Q bounce: C-layout -> A-fragments via per-wave LDS, 2 passes ----
    u16* myQb = Qb + wid * 2048;
    bf16x8 aqh[2][2], aql[2][2];
    #pragma unroll
    for (int mf = 0; mf < 2; ++mf)
    #pragma unroll
    for (int f = 0; f < 4; ++f)
    #pragma unroll
    for (int rr = 0; rr < 4; ++rr) {
        int r = mf * 16 + 4 * g + rr;
        int c = f * 16 + r16;
        myQb[r * 64 + (((c >> 3) ^ (r & 7)) << 3) + (c & 7)] = f2b(acc[mf][f][rr]);
    }
    #pragma unroll
    for (int mf = 0; mf < 2; ++mf)
    #pragma unroll
    for (int k2 = 0; k2 < 2; ++k2) {
        int r = mf * 16 + r16;
        aqh[mf][k2] = *(const bf16x8*)&myQb[r * 64 + (((k2 * 4 + g) ^ (r & 7)) << 3)];
    }
    __builtin_amdgcn_sched_barrier(0);   // keep lo-pass writes after hi-pass reads
    #pragma unroll
    for (int mf = 0; mf < 2; ++mf)
    #pragma unroll
    for (int f = 0; f < 4; ++f)
    #pragma unroll
    for (int rr = 0; rr < 4; ++rr) {
        int r = mf * 16 + 4 * g + rr;
        int c = f * 16 + r16;
        float v = acc[mf][f][rr];
        bf16_t hi = (bf16_t)v;
        myQb[r * 64 + (((c >> 3) ^ (r & 7)) << 3) + (c & 7)] = f2b(v - (float)hi);
    }
    #pragma unroll
    for (int mf = 0; mf < 2; ++mf)
    #pragma unroll
    for (int k2 = 0; k2 < 2; ++k2) {
        int r = mf * 16 + r16;
        aql[mf][k2] = *(const bf16x8*)&myQb[r * 64 + (((k2 * 4 + g) ^ (r & 7)) << 3)];
    }

    __syncthreads();   // Kh/Kl/Vt now visible block-wide

    // ---------------- phase 2: S = Q K^T (split, 3 MFMA) -------------------
    f32x4 S[2][16];
    #pragma unroll
    for (int mf = 0; mf < 2; ++mf)
        #pragma unroll
        for (int nf = 0; nf < 16; ++nf) S[mf][nf] = f32x4{0.f,0.f,0.f,0.f};

    #pragma unroll
    for (int nf = 0; nf < 16; ++nf) {
        int q = nf * 16 + r16;
        #pragma unroll
        for (int k2 = 0; k2 < 2; ++k2) {
            int e = q * 64 + (((k2 * 4 + g) ^ (q & 7)) << 3);
            bf16x8 kh = *(const bf16x8*)&Kh[e];
            bf16x8 kl = *(const bf16x8*)&Kl[e];
            S[0][nf] = mfma(aqh[0][k2], kh, S[0][nf]);
            S[1][nf] = mfma(aqh[1][k2], kh, S[1][nf]);
            S[0][nf] = mfma(aqh[0][k2], kl, S[0][nf]);
            S[1][nf] = mfma(aqh[1][k2], kl, S[1][nf]);
            S[0][nf] = mfma(aql[0][k2], kh, S[0][nf]);
            S[1][nf] = mfma(aql[1][k2], kh, S[1][nf]);
        }
    }

    // ---------------- softmax (rows lane-spread over 16 lanes) -------------
    float inv_[2][4];
    #pragma unroll
    for (int mf = 0; mf < 2; ++mf) {
        float mrow[4] = {-1e30f,-1e30f,-1e30f,-1e30f};
        #pragma unroll
        for (int nf = 0; nf < 16; ++nf)
            #pragma unroll
            for (int rr = 0; rr < 4; ++rr) mrow[rr] = fmaxf(mrow[rr], S[mf][nf][rr]);
        #pragma unroll
        for (int mask = 1; mask < 16; mask <<= 1)
            #pragma unroll
            for (int rr = 0; rr < 4; ++rr) mrow[rr] = fmaxf(mrow[rr], __shfl_xor(mrow[rr], mask, 64));
        float ssum[4] = {0.f,0.f,0.f,0.f};
        #pragma unroll
        for (int nf = 0; nf < 16; ++nf)
            #pragma unroll
            for (int rr = 0; rr < 4; ++rr) {
                float p = __expf((S[mf][nf][rr] - mrow[rr]) * 64.0f);  // scale = D
                S[mf][nf][rr] = p;
                ssum[rr] += p;
            }
        #pragma unroll
        for (int mask = 1; mask < 16; mask <<= 1)
            #pragma unroll
            for (int rr = 0; rr < 4; ++rr) ssum[rr] += __shfl_xor(ssum[rr], mask, 64);
        #pragma unroll
        for (int rr = 0; rr < 4; ++rr) inv_[mf][rr] = 1.0f / ssum[rr];
    }

    // ---------------- phase 3: O = P V (per-wave double-buffered bounce) ---
    f32x4 O[2][4];
    #pragma unroll
    for (int mf = 0; mf < 2; ++mf)
        #pragma unroll
        for (int f = 0; f < 4; ++f) O[mf][f] = f32x4{0.f,0.f,0.f,0.f};

    for (int t = 0; t < 8; ++t) {
        u16* pb = myQb + (t & 1) * 1024;         // [32][32] per buffer
        #pragma unroll
        for (int mf = 0; mf < 2; ++mf)
        #pragma unroll
        for (int tt = 0; tt < 2; ++tt) {
            int nf = 2 * t + tt;
            #pragma unroll
            for (int rr = 0; rr < 4; ++rr)
                pb[(mf * 16 + 4 * g + rr) * 32 + tt * 16 + r16] = f2b(S[mf][nf][rr] * inv_[mf][rr]);
        }
        bf16x8 ap0 = *(const bf16x8*)&pb[(r16) * 32 + 8 * g];
        bf16x8 ap1 = *(const bf16x8*)&pb[(16 + r16) * 32 + 8 * g];
        #pragma unroll
        for (int f = 0; f < 4; ++f) {
            int d = f * 16 + r16;
            int e = d * 256 + ((((t * 32 + 8 * g) >> 3) ^ (d & 7)) << 3);
            bf16x8 bv = *(const bf16x8*)&Vt[e];
            O[0][f] = mfma(ap0, bv, O[0][f]);
            O[1][f] = mfma(ap1, bv, O[1][f]);
        }
    }

    #pragma unroll
    for (int mf = 0; mf < 2; ++mf)
    #pragma unroll
    for (int f = 0; f < 4; ++f)
    #pragma unroll
    for (int rr = 0; rr < 4; ++rr)
        attn[(row0 + m0w + mf * 16 + 4 * g + rr) * C_ + h * 64 + f * 16 + r16] = f2b(O[mf][f][rr]);
}

// ---------------------------------------------------------------------------
// proj: attn(65536x384 bf16) @ w_proj(384x384) + bias -> f32 out.
// ---------------------------------------------------------------------------
__global__ __launch_bounds__(256, 2) void proj_kernel(
    const u16* __restrict__ attn, const u16* __restrict__ wPt,
    const float* __restrict__ bias, float* __restrict__ out)
{
    __shared__ alignas(16) u16 As[128*32];
    __shared__ alignas(16) u16 Bs[128*32];

    const int tid = threadIdx.x;
    const int lane = tid & 63, wid = tid >> 6;
    const int wr = wid >> 1, wc = wid & 1;
    const int g = lane >> 4, r16 = lane & 15;
    const int m0 = blockIdx.x * 128;
    const int n0 = blockIdx.y * 128;

    f32x4 acc[4][4];
    for (int i = 0; i < 4; i++) for (int j = 0; j < 4; j++) acc[i][j] = f32x4{0.f,0.f,0.f,0.f};

    for (int kt = 0; kt < C_; kt += 32) {
        for (int r = 0; r < 4; ++r) {
            int i = tid + 256*r;
            int mm = i >> 3;
            int kk = (i & 7) << 2;
            u16x4 v = *(const u16x4*)&attn[(size_t)(m0+mm)*C_ + kt + kk];
            int e = mm*32 + (((kk>>3) ^ ((mm>>1)&3))<<3) + (kk&7);
            *(u16x4*)&As[e] = v;
        }
        for (int r = 0; r < 4; ++r) {
            int i = tid + 256*r;
            int nn = i >> 3;
            int kk = (i & 7) << 2;
            u16x4 v = *(const u16x4*)&wPt[(size_t)(n0+nn)*C_ + kt + kk];
            int e = nn*32 + (((kk>>3) ^ ((nn>>1)&3))<<3) + (kk&7);
            *(u16x4*)&Bs[e] = v;
        }
        __syncthreads();

        bf16x8 a[4], b[4];
        for (int i = 0; i < 4; i++) {
            int row = wr*64 + i*16 + r16;
            a[i] = *(const bf16x8*)&As[row*32 + ((g ^ ((row>>1)&3))<<3)];
        }
        for (int j = 0; j < 4; j++) {
            int n = wc*64 + j*16 + r16;
            b[j] = *(const bf16x8*)&Bs[n*32 + ((g ^ ((n>>1)&3))<<3)];
        }
        for (int i = 0; i < 4; i++) for (int j = 0; j < 4; j++)
            acc[i][j] = mfma(a[i], b[j], acc[i][j]);
        __syncthreads();
    }

    for (int i = 0; i < 4; i++) for (int j = 0; j < 4; j++) for (int rr = 0; rr < 4; rr++) {
        size_t row = m0 + wr*64 + i*16 + g*4 + rr;
        int col = n0 + wc*64 + j*16 + r16;
        out[row*C_ + col] = acc[i][j][rr] + bias[col];
    }
}

// ---------------------------------------------------------------------------
extern "C" void kernel_launch(void* const* d_in, const int* in_sizes, int n_in,
                              void* d_out, int out_size, void* d_ws, size_t ws_size,
                              hipStream_t stream)
{
    const float* x      = (const float*)d_in[0];
    const float* w_qkv  = (const float*)d_in[1];
    const float* w_proj = (const float*)d_in[2];
    const float* b_proj = (const float*)d_in[3];
    float* out = (float*)d_out;

    u16* ws = (u16*)d_ws;
    u16* attnb = ws;                                  // 65536*384 u16 = 50 MB
    size_t off = (size_t)M_TOTAL * C_;
    u16* Wfh = ws + off; off += (size_t)H_ * WF_HSTRIDE;
    u16* Wfl = ws + off; off += (size_t)H_ * WF_HSTRIDE;
    u16* wPt = ws + off; off += (size_t)C_ * C_;

    hipFuncSetAttribute((const void*)fused_attn,
                        hipFuncAttributeMaxDynamicSharedMemorySize, FUSED_LDS);

    int prep_n = H_ * KSTEPS * NFRAG * 64 + C_ * C_;
    prep_w<<<dim3((prep_n + 255) / 256), 256, 0, stream>>>(w_qkv, w_proj, Wfh, Wfl, wPt);
    fused_attn<<<dim3(H_, B_ * N_), 512, FUSED_LDS, stream>>>(x, Wfh, Wfl, attnb);
    proj_kernel<<<dim3(M_TOTAL / 128, C_ / 128), 256, 0, stream>>>(attnb, wPt, b_proj, out);
}

// Round 3
// 282.324 us; speedup vs baseline: 1.9088x; 1.0753x over previous
//
#include <hip/hip_runtime.h>

typedef __bf16 bf16_t;
typedef __bf16 bf16x8 __attribute__((ext_vector_type(8)));
typedef float f32x4 __attribute__((ext_vector_type(4)));
typedef unsigned short u16;
typedef unsigned short u16x4 __attribute__((ext_vector_type(4)));
typedef unsigned int u32;

#define B_ 4
#define N_ 64
#define P_ 256
#define C_ 384
#define H_ 6
#define D_ 64
#define M_TOTAL 65536
#define NQKV 1152
#define KSTEPS 12                     // 384/32
#define NFRAG 12                      // 192/16 (Q|K|V cols per head)
#define WF_HSTRIDE (KSTEPS*NFRAG*512) // u16 per head in frag-packed weights
#define FUSED_LDS 131072
#define NBLK (H_*B_*N_)               // 1536 = 8 XCDs * 192

__device__ __forceinline__ u16 f2b(float f){ return __builtin_bit_cast(u16, (bf16_t)f); }
__device__ __forceinline__ f32x4 mfma(bf16x8 a, bf16x8 b, f32x4 c){
    return __builtin_amdgcn_mfma_f32_16x16x32_bf16(a, b, c, 0, 0, 0);
}

// ---------------------------------------------------------------------------
// prep: (a) per-head fragment-packed split weights Wfh/Wfl[h][ks][nf][lane][8]
//       (b) w_proj^T bf16 for the proj GEMM
// ---------------------------------------------------------------------------
__global__ __launch_bounds__(256) void prep_w(
    const float* __restrict__ wqkv, const float* __restrict__ wproj,
    u16* __restrict__ Wfh, u16* __restrict__ Wfl, u16* __restrict__ wPt)
{
    int i = blockIdx.x * 256 + threadIdx.x;
    const int NSLOT = H_ * KSTEPS * NFRAG * 64;   // 55296
    if (i < NSLOT) {
        int lane = i & 63;
        int frag = i >> 6;
        int nf = frag % NFRAG;
        int ks = (frag / NFRAG) % KSTEPS;
        int h  = frag / (NFRAG * KSTEPS);
        int part = nf >> 2;                        // 0=Q 1=K 2=V
        int nh   = (nf & 3) * 16 + (lane & 15);    // 0..63 within head
        int col  = part * C_ + h * 64 + nh;        // col in w_qkv
        int k0   = ks * 32 + (lane >> 4) * 8;
        #pragma unroll
        for (int e = 0; e < 8; ++e) {
            float w = wqkv[(size_t)(k0 + e) * NQKV + col];
            bf16_t hi = (bf16_t)w;
            Wfh[(size_t)i * 8 + e] = __builtin_bit_cast(u16, hi);
            Wfl[(size_t)i * 8 + e] = f2b(w - (float)hi);
        }
    }
    int j = i - NSLOT;
    if (j >= 0 && j < C_ * C_) {
        int k = j / C_, n = j % C_;
        wPt[(size_t)n * C_ + k] = f2b(wproj[j]);
    }
}

// ---------------------------------------------------------------------------
// fused per-(h, b*n) kernel: QKV projection (split bf16) + attention.
// 512 threads = 8 waves; wave owns 32 q-rows. One __syncthreads total.
// Occupancy is structurally 2 waves/SIMD (S needs 128 f32/lane) -> pin
// waves_per_eu(2,2) so the compiler uses the full 256-VGPR budget for ILP.
// ---------------------------------------------------------------------------
__global__ __launch_bounds__(512)
__attribute__((amdgpu_waves_per_eu(2, 2)))
void fused_attn(
    const float* __restrict__ x, const u16* __restrict__ Wfh,
    const u16* __restrict__ Wfl, u16* __restrict__ attn)
{
    extern __shared__ u16 sm[];
    u16* Kh = sm;              // [256][64] swizzled, 32 KB
    u16* Kl = sm + 16384;      // 32 KB
    u16* Vt = sm + 32768;      // [64][256] swizzled, 32 KB
    u16* Qb = sm + 49152;      // 8 waves x 2048 u16 (Q bounce; reused as P bounce)

    const int tid  = threadIdx.x;
    const int lane = tid & 63, wid = tid >> 6;
    const int g = lane >> 4, r16 = lane & 15;

    // XCD-chunk swizzle (bijective: 1536 = 8 * 192): all 6 heads of a bn --
    // and 32 neighboring bn -- land on one XCD's L2, so the X slab is
    // HBM-fetched once instead of 6 times.
    const int p = blockIdx.x;
    const int logical = (p & 7) * (NBLK / 8) + (p >> 3);
    const int h  = logical % H_;
    const int bn = logical / H_;
    const size_t row0 = (size_t)bn * P_;
    const int m0w = wid * 32;

    // ---------------- phase 1: [Q|K|V] = X_slab @ W3head, split bf16 -------
    f32x4 acc[2][12];
    #pragma unroll
    for (int mf = 0; mf < 2; ++mf)
        #pragma unroll
        for (int nf = 0; nf < 12; ++nf) acc[mf][nf] = f32x4{0.f,0.f,0.f,0.f};

    const float* xr0 = x + (row0 + m0w + r16) * C_;
    const float* xr1 = xr0 + 16 * C_;
    const u16* wh = Wfh + (size_t)h * WF_HSTRIDE + lane * 8;
    const u16* wl = Wfl + (size_t)h * WF_HSTRIDE + lane * 8;

    #pragma unroll
    for (int ks = 0; ks < KSTEPS; ++ks) {
        // ---- load ALL operands for this k-step first (lets the scheduler
        //      hoist next-step loads over this step's MFMAs) ----
        const u16* whk = wh + ks * (NFRAG * 512);
        const u16* wlk = wl + ks * (NFRAG * 512);
        bf16x8 bh[12], bl[8];
        #pragma unroll
        for (int nf = 0; nf < 12; ++nf) bh[nf] = *(const bf16x8*)(whk + nf * 512);
        #pragma unroll
        for (int nf = 0; nf < 8; ++nf)  bl[nf] = *(const bf16x8*)(wlk + nf * 512);

        const float* xp0 = xr0 + ks * 32 + 8 * g;
        const float* xp1 = xr1 + ks * 32 + 8 * g;
        f32x4 a0 = *(const f32x4*)xp0, b0 = *(const f32x4*)(xp0 + 4);
        f32x4 a1 = *(const f32x4*)xp1, b1 = *(const f32x4*)(xp1 + 4);

        bf16x8 ah[2], al[2];
        #pragma unroll
        for (int e = 0; e < 4; ++e) {
            bf16_t h0 = (bf16_t)a0[e], h1 = (bf16_t)b0[e];
            ah[0][e] = h0;   al[0][e]   = (bf16_t)(a0[e] - (float)h0);
            ah[0][4+e] = h1; al[0][4+e] = (bf16_t)(b0[e] - (float)h1);
            bf16_t h2 = (bf16_t)a1[e], h3 = (bf16_t)b1[e];
            ah[1][e] = h2;   al[1][e]   = (bf16_t)(a1[e] - (float)h2);
            ah[1][4+e] = h3; al[1][4+e] = (bf16_t)(b1[e] - (float)h3);
        }

        // ---- MFMAs: Q,K (nf 0..7) split 3x, V (nf 8..11) plain ----
        #pragma unroll
        for (int nf = 0; nf < 8; ++nf) {
            acc[0][nf] = mfma(ah[0], bh[nf], acc[0][nf]);
            acc[1][nf] = mfma(ah[1], bh[nf], acc[1][nf]);
            acc[0][nf] = mfma(ah[0], bl[nf], acc[0][nf]);
            acc[1][nf] = mfma(ah[1], bl[nf], acc[1][nf]);
            acc[0][nf] = mfma(al[0], bh[nf], acc[0][nf]);
            acc[1][nf] = mfma(al[1], bh[nf], acc[1][nf]);
        }
        #pragma unroll
        for (int nf = 8; nf < 12; ++nf) {
            acc[0][nf] = mfma(ah[0], bh[nf], acc[0][nf]);
            acc[1][nf] = mfma(ah[1], bh[nf], acc[1][nf]);
        }
    }

    // ---- epilogue: K -> Kh/Kl (split), V -> Vt (transposed), swizzled ----
    #pragma unroll
    for (int mf = 0; mf < 2; ++mf)
    #pragma unroll
    for (int f = 0; f < 4; ++f)
    #pragma unroll
    for (int rr = 0; rr < 4; ++rr) {
        int q = m0w + mf * 16 + 4 * g + rr;
        int d = f * 16 + r16;
        int ek = q * 64 + (((d >> 3) ^ (q & 7)) << 3) + (d & 7);
        float kv = acc[mf][4 + f][rr];
        bf16_t khi = (bf16_t)kv;
        Kh[ek] = __builtin_bit_cast(u16, khi);
        Kl[ek] = f2b(kv - (float)khi);
        Vt[d * 256 + (((q >> 3) ^ (d & 7)) << 3) + (q & 7)] = f2b(acc[mf][8 + f][rr]);
    }

    // ---- Q bounce: C-layout -> A-fragments via per-wave LDS, 2 passes ----
    u16* myQb = Qb + wid * 2048;
    bf16x8 aqh[2][2], aql[2][2];
    #pragma unroll
    for (int mf = 0; mf < 2; ++mf)
    #pragma unroll
    for (int f = 0; f < 4; ++f)
    #pragma unroll
    for (int rr = 0; rr < 4; ++rr) {
        int r = mf * 16 + 4 * g + rr;
        int c = f * 16 + r16;
        myQb[r * 64 + (((c >> 3) ^ (r & 7)) << 3) + (c & 7)] = f2b(acc[mf][f][rr]);
    }
    #pragma unroll
    for (int mf = 0; mf < 2; ++mf)
    #pragma unroll
    for (int k2 = 0; k2 < 2; ++k2) {
        int r = mf * 16 + r16;
        aqh[mf][k2] = *(const bf16x8*)&myQb[r * 64 + (((k2 * 4 + g) ^ (r & 7)) << 3)];
    }
    __builtin_amdgcn_sched_barrier(0);   // keep lo-pass writes after hi-pass reads
    #pragma unroll
    for (int mf = 0; mf < 2; ++mf)
    #pragma unroll
    for (int f = 0; f < 4; ++f)
    #pragma unroll
    for (int rr = 0; rr < 4; ++rr) {
        int r = mf * 16 + 4 * g + rr;
        int c = f * 16 + r16;
        float v = acc[mf][f][rr];
        bf16_t hi = (bf16_t)v;
        myQb[r * 64 + (((c >> 3) ^ (r & 7)) << 3) + (c & 7)] = f2b(v - (float)hi);
    }
    #pragma unroll
    for (int mf = 0; mf < 2; ++mf)
    #pragma unroll
    for (int k2 = 0; k2 < 2; ++k2) {
        int r = mf * 16 + r16;
        aql[mf][k2] = *(const bf16x8*)&myQb[r * 64 + (((k2 * 4 + g) ^ (r & 7)) << 3)];
    }

    __syncthreads();   // Kh/Kl/Vt now visible block-wide

    // ---------------- phase 2: S = Q K^T (split, 3 MFMA) -------------------
    f32x4 S[2][16];
    #pragma unroll
    for (int mf = 0; mf < 2; ++mf)
        #pragma unroll
        for (int nf = 0; nf < 16; ++nf) S[mf][nf] = f32x4{0.f,0.f,0.f,0.f};

    #pragma unroll
    for (int nf = 0; nf < 16; ++nf) {
        int q = nf * 16 + r16;
        bf16x8 kh[2], kl[2];
        #pragma unroll
        for (int k2 = 0; k2 < 2; ++k2) {
            int e = q * 64 + (((k2 * 4 + g) ^ (q & 7)) << 3);
            kh[k2] = *(const bf16x8*)&Kh[e];
            kl[k2] = *(const bf16x8*)&Kl[e];
        }
        #pragma unroll
        for (int k2 = 0; k2 < 2; ++k2) {
            S[0][nf] = mfma(aqh[0][k2], kh[k2], S[0][nf]);
            S[1][nf] = mfma(aqh[1][k2], kh[k2], S[1][nf]);
            S[0][nf] = mfma(aqh[0][k2], kl[k2], S[0][nf]);
            S[1][nf] = mfma(aqh[1][k2], kl[k2], S[1][nf]);
            S[0][nf] = mfma(aql[0][k2], kh[k2], S[0][nf]);
            S[1][nf] = mfma(aql[1][k2], kh[k2], S[1][nf]);
        }
    }

    // ---------------- softmax (rows lane-spread over 16 lanes) -------------
    float inv_[2][4];
    #pragma unroll
    for (int mf = 0; mf < 2; ++mf) {
        float mrow[4] = {-1e30f,-1e30f,-1e30f,-1e30f};
        #pragma unroll
        for (int nf = 0; nf < 16; ++nf)
            #pragma unroll
            for (int rr = 0; rr < 4; ++rr) mrow[rr] = fmaxf(mrow[rr], S[mf][nf][rr]);
        #pragma unroll
        for (int mask = 1; mask < 16; mask <<= 1)
            #pragma unroll
            for (int rr = 0; rr < 4; ++rr) mrow[rr] = fmaxf(mrow[rr], __shfl_xor(mrow[rr], mask, 64));
        float ssum[4] = {0.f,0.f,0.f,0.f};
        #pragma unroll
        for (int nf = 0; nf < 16; ++nf)
            #pragma unroll
            for (int rr = 0; rr < 4; ++rr) {
                float pv = __expf((S[mf][nf][rr] - mrow[rr]) * 64.0f);  // scale = D
                S[mf][nf][rr] = pv;
                ssum[rr] += pv;
            }
        #pragma unroll
        for (int mask = 1; mask < 16; mask <<= 1)
            #pragma unroll
            for (int rr = 0; rr < 4; ++rr) ssum[rr] += __shfl_xor(ssum[rr], mask, 64);
        #pragma unroll
        for (int rr = 0; rr < 4; ++rr) inv_[mf][rr] = 1.0f / ssum[rr];
    }

    // ---------------- phase 3: O = P V (per-wave double-buffered bounce) ---
    f32x4 O[2][4];
    #pragma unroll
    for (int mf = 0; mf < 2; ++mf)
        #pragma unroll
        for (int f = 0; f < 4; ++f) O[mf][f] = f32x4{0.f,0.f,0.f,0.f};

    #pragma unroll
    for (int t = 0; t < 8; ++t) {
        // V fragments first: independent of the P-bounce writes below, so
        // they issue early and their lgkm latency hides under the writes.
        bf16x8 bv[4];
        #pragma unroll
        for (int f = 0; f < 4; ++f) {
            int d = f * 16 + r16;
            bv[f] = *(const bf16x8*)&Vt[d * 256 + ((((t * 32 + 8 * g) >> 3) ^ (d & 7)) << 3)];
        }
        u16* pb = myQb + (t & 1) * 1024;         // [32][32] per buffer
        #pragma unroll
        for (int mf = 0; mf < 2; ++mf)
        #pragma unroll
        for (int tt = 0; tt < 2; ++tt) {
            int nf = 2 * t + tt;
            #pragma unroll
            for (int rr = 0; rr < 4; ++rr)
                pb[(mf * 16 + 4 * g + rr) * 32 + tt * 16 + r16] = f2b(S[mf][nf][rr] * inv_[mf][rr]);
        }
        bf16x8 ap0 = *(const bf16x8*)&pb[(r16) * 32 + 8 * g];
        bf16x8 ap1 = *(const bf16x8*)&pb[(16 + r16) * 32 + 8 * g];
        #pragma unroll
        for (int f = 0; f < 4; ++f) {
            O[0][f] = mfma(ap0, bv[f], O[0][f]);
            O[1][f] = mfma(ap1, bv[f], O[1][f]);
        }
    }

    #pragma unroll
    for (int mf = 0; mf < 2; ++mf)
    #pragma unroll
    for (int f = 0; f < 4; ++f)
    #pragma unroll
    for (int rr = 0; rr < 4; ++rr)
        attn[(row0 + m0w + mf * 16 + 4 * g + rr) * C_ + h * 64 + f * 16 + r16] = f2b(O[mf][f][rr]);
}

// ---------------------------------------------------------------------------
// proj: attn(65536x384 bf16) @ w_proj(384x384) + bias -> f32 out.
// ---------------------------------------------------------------------------
__global__ __launch_bounds__(256, 2) void proj_kernel(
    const u16* __restrict__ attn, const u16* __restrict__ wPt,
    const float* __restrict__ bias, float* __restrict__ out)
{
    __shared__ alignas(16) u16 As[128*32];
    __shared__ alignas(16) u16 Bs[128*32];

    const int tid = threadIdx.x;
    const int lane = tid & 63, wid = tid >> 6;
    const int wr = wid >> 1, wc = wid & 1;
    const int g = lane >> 4, r16 = lane & 15;
    const int m0 = blockIdx.x * 128;
    const int n0 = blockIdx.y * 128;

    f32x4 acc[4][4];
    for (int i = 0; i < 4; i++) for (int j = 0; j < 4; j++) acc[i][j] = f32x4{0.f,0.f,0.f,0.f};

    for (int kt = 0; kt < C_; kt += 32) {
        for (int r = 0; r < 4; ++r) {
            int i = tid + 256*r;
            int mm = i >> 3;
            int kk = (i & 7) << 2;
            u16x4 v = *(const u16x4*)&attn[(size_t)(m0+mm)*C_ + kt + kk];
            int e = mm*32 + (((kk>>3) ^ ((mm>>1)&3))<<3) + (kk&7);
            *(u16x4*)&As[e] = v;
        }
        for (int r = 0; r < 4; ++r) {
            int i = tid + 256*r;
            int nn = i >> 3;
            int kk = (i & 7) << 2;
            u16x4 v = *(const u16x4*)&wPt[(size_t)(n0+nn)*C_ + kt + kk];
            int e = nn*32 + (((kk>>3) ^ ((nn>>1)&3))<<3) + (kk&7);
            *(u16x4*)&Bs[e] = v;
        }
        __syncthreads();

        bf16x8 a[4], b[4];
        for (int i = 0; i < 4; i++) {
            int row = wr*64 + i*16 + r16;
            a[i] = *(const bf16x8*)&As[row*32 + ((g ^ ((row>>1)&3))<<3)];
        }
        for (int j = 0; j < 4; j++) {
            int n = wc*64 + j*16 + r16;
            b[j] = *(const bf16x8*)&Bs[n*32 + ((g ^ ((n>>1)&3))<<3)];
        }
        for (int i = 0; i < 4; i++) for (int j = 0; j < 4; j++)
            acc[i][j] = mfma(a[i], b[j], acc[i][j]);
        __syncthreads();
    }

    for (int i = 0; i < 4; i++) for (int j = 0; j < 4; j++) for (int rr = 0; rr < 4; rr++) {
        size_t row = m0 + wr*64 + i*16 + g*4 + rr;
        int col = n0 + wc*64 + j*16 + r16;
        out[row*C_ + col] = acc[i][j][rr] + bias[col];
    }
}

// ---------------------------------------------------------------------------
extern "C" void kernel_launch(void* const* d_in, const int* in_sizes, int n_in,
                              void* d_out, int out_size, void* d_ws, size_t ws_size,
                              hipStream_t stream)
{
    const float* x      = (const float*)d_in[0];
    const float* w_qkv  = (const float*)d_in[1];
    const float* w_proj = (const float*)d_in[2];
    const float* b_proj = (const float*)d_in[3];
    float* out = (float*)d_out;

    u16* ws = (u16*)d_ws;
    u16* attnb = ws;                                  // 65536*384 u16 = 50 MB
    size_t off = (size_t)M_TOTAL * C_;
    u16* Wfh = ws + off; off += (size_t)H_ * WF_HSTRIDE;
    u16* Wfl = ws + off; off += (size_t)H_ * WF_HSTRIDE;
    u16* wPt = ws + off; off += (size_t)C_ * C_;

    hipFuncSetAttribute((const void*)fused_attn,
                        hipFuncAttributeMaxDynamicSharedMemorySize, FUSED_LDS);

    int prep_n = H_ * KSTEPS * NFRAG * 64 + C_ * C_;
    prep_w<<<dim3((prep_n + 255) / 256), 256, 0, stream>>>(w_qkv, w_proj, Wfh, Wfl, wPt);
    fused_attn<<<dim3(NBLK), 512, FUSED_LDS, stream>>>(x, Wfh, Wfl, attnb);
    proj_kernel<<<dim3(M_TOTAL / 128, C_ / 128), 256, 0, stream>>>(attnb, wPt, b_proj, out);
}

// Round 4
// 281.278 us; speedup vs baseline: 1.9159x; 1.0037x over previous
//
#include <hip/hip_runtime.h>

typedef __bf16 bf16_t;
typedef __bf16 bf16x8 __attribute__((ext_vector_type(8)));
typedef float f32x4 __attribute__((ext_vector_type(4)));
typedef unsigned short u16;
typedef unsigned short u16x4 __attribute__((ext_vector_type(4)));
typedef unsigned int u32;

#define B_ 4
#define N_ 64
#define P_ 256
#define C_ 384
#define H_ 6
#define D_ 64
#define M_TOTAL 65536
#define NQKV 1152
#define KSTEPS 12                     // 384/32
#define NFRAG 12                      // 192/16 (Q|K|V cols per head)
#define WF_HSTRIDE (KSTEPS*NFRAG*512) // u16 per head in frag-packed weights
#define NBLK (H_*B_*N_)               // 1536 = 8 XCDs * 192
// LDS: Kh 32K + Kl 32K + Vt 32K + 8 waves * 5120B bounce = 136 KB
#define FUSED_LDS 139264
#define PB_STRIDE 40                  // P-bounce row stride (u16): 80B, 16B-mult, kills 8-way conflict
#define SB() __builtin_amdgcn_sched_barrier(0)

__device__ __forceinline__ u16 f2b(float f){ return __builtin_bit_cast(u16, (bf16_t)f); }
__device__ __forceinline__ f32x4 mfma(bf16x8 a, bf16x8 b, f32x4 c){
    return __builtin_amdgcn_mfma_f32_16x16x32_bf16(a, b, c, 0, 0, 0);
}

// ---------------------------------------------------------------------------
// prep: (a) per-head fragment-packed split weights Wfh/Wfl[h][ks][nf][lane][8]
//       (b) w_proj^T bf16 for the proj GEMM
// ---------------------------------------------------------------------------
__global__ __launch_bounds__(256) void prep_w(
    const float* __restrict__ wqkv, const float* __restrict__ wproj,
    u16* __restrict__ Wfh, u16* __restrict__ Wfl, u16* __restrict__ wPt)
{
    int i = blockIdx.x * 256 + threadIdx.x;
    const int NSLOT = H_ * KSTEPS * NFRAG * 64;   // 55296
    if (i < NSLOT) {
        int lane = i & 63;
        int frag = i >> 6;
        int nf = frag % NFRAG;
        int ks = (frag / NFRAG) % KSTEPS;
        int h  = frag / (NFRAG * KSTEPS);
        int part = nf >> 2;                        // 0=Q 1=K 2=V
        int nh   = (nf & 3) * 16 + (lane & 15);    // 0..63 within head
        int col  = part * C_ + h * 64 + nh;        // col in w_qkv
        int k0   = ks * 32 + (lane >> 4) * 8;
        #pragma unroll
        for (int e = 0; e < 8; ++e) {
            float w = wqkv[(size_t)(k0 + e) * NQKV + col];
            bf16_t hi = (bf16_t)w;
            Wfh[(size_t)i * 8 + e] = __builtin_bit_cast(u16, hi);
            Wfl[(size_t)i * 8 + e] = f2b(w - (float)hi);
        }
    }
    int j = i - NSLOT;
    if (j >= 0 && j < C_ * C_) {
        int k = j / C_, n = j % C_;
        wPt[(size_t)n * C_ + k] = f2b(wproj[j]);
    }
}

// ---------------------------------------------------------------------------
// fused per-(h, b*n) kernel: QKV projection (split bf16) + attention.
// 512 threads = 8 waves; wave owns 32 q-rows. Manually software-pipelined:
// per k-step, next-step loads are issued in fenced sections between MFMA
// packets (ping-pong register buffers, static parity indexing).
// ---------------------------------------------------------------------------
__global__ __launch_bounds__(512)
__attribute__((amdgpu_waves_per_eu(2, 2)))
void fused_attn(
    const float* __restrict__ x, const u16* __restrict__ Wfh,
    const u16* __restrict__ Wfl, u16* __restrict__ attn)
{
    extern __shared__ u16 sm[];
    u16* Kh = sm;              // [256][64] swizzled, 32 KB
    u16* Kl = sm + 16384;      // 32 KB
    u16* Vt = sm + 32768;      // [64][256] swizzled, 32 KB
    u16* Qb = sm + 49152;      // 8 waves x 2560 u16 (Q bounce + P double-buffer)

    const int tid  = threadIdx.x;
    const int lane = tid & 63, wid = tid >> 6;
    const int g = lane >> 4, r16 = lane & 15;

    // XCD-chunk swizzle (bijective: 1536 = 8 * 192)
    const int p = blockIdx.x;
    const int logical = (p & 7) * (NBLK / 8) + (p >> 3);
    const int h  = logical % H_;
    const int bn = logical / H_;
    const size_t row0 = (size_t)bn * P_;
    const int m0w = wid * 32;

    // ---------------- phase 1: [Q|K|V] = X_slab @ W3head, split bf16 -------
    f32x4 acc[2][12];
    #pragma unroll
    for (int mf = 0; mf < 2; ++mf)
        #pragma unroll
        for (int nf = 0; nf < 12; ++nf) acc[mf][nf] = f32x4{0.f,0.f,0.f,0.f};

    const float* xr0 = x + (row0 + m0w + r16) * C_;
    const float* xr1 = xr0 + 16 * C_;
    const u16* wh = Wfh + (size_t)h * WF_HSTRIDE + lane * 8;
    const u16* wl = Wfl + (size_t)h * WF_HSTRIDE + lane * 8;

    bf16x8 bhv[2][12];       // hi-plane weight frags, ping-pong by ks parity
    bf16x8 blv[2][8];        // lo-plane (Q,K only)
    bf16x8 ahq[2][2], alq[2][2];   // x split frags [parity][mf]
    f32x4 xr[4];             // raw x for next ks

    // helper: split 4 raw f32x4 (2 rows x 8 floats) into hi/lo bf16x8 frags
#define SPLIT_A(par) do {                                                    \
    _Pragma("unroll")                                                        \
    for (int e = 0; e < 4; ++e) {                                            \
        bf16_t h0 = (bf16_t)xr[0][e], h1 = (bf16_t)xr[1][e];                 \
        ahq[par][0][e]   = h0; alq[par][0][e]   = (bf16_t)(xr[0][e] - (float)h0); \
        ahq[par][0][4+e] = h1; alq[par][0][4+e] = (bf16_t)(xr[1][e] - (float)h1); \
        bf16_t h2 = (bf16_t)xr[2][e], h3 = (bf16_t)xr[3][e];                 \
        ahq[par][1][e]   = h2; alq[par][1][e]   = (bf16_t)(xr[2][e] - (float)h2); \
        ahq[par][1][4+e] = h3; alq[par][1][4+e] = (bf16_t)(xr[3][e] - (float)h3); \
    } } while (0)

#define XLOAD(ks_) do {                                                      \
    const float* _xp0 = xr0 + (ks_) * 32 + 8 * g;                            \
    const float* _xp1 = xr1 + (ks_) * 32 + 8 * g;                            \
    xr[0] = *(const f32x4*)_xp0; xr[1] = *(const f32x4*)(_xp0 + 4);          \
    xr[2] = *(const f32x4*)_xp1; xr[3] = *(const f32x4*)(_xp1 + 4);          \
    } while (0)

    // prologue: everything for ks=0
    XLOAD(0);
    {
        const u16* whk = wh;  const u16* wlk = wl;
        #pragma unroll
        for (int nf = 0; nf < 12; ++nf) bhv[0][nf] = *(const bf16x8*)(whk + nf * 512);
        #pragma unroll
        for (int nf = 0; nf < 8;  ++nf) blv[0][nf] = *(const bf16x8*)(wlk + nf * 512);
    }
    SPLIT_A(0);

    #pragma unroll
    for (int ks = 0; ks < KSTEPS; ++ks) {
        const int par = ks & 1, nxt = par ^ 1;
        const u16* whk1 = wh + (ks + 1) * (NFRAG * 512);
        const u16* wlk1 = wl + (ks + 1) * (NFRAG * 512);

        // S_A: x(ks+1) + GA-hi(ks+1)
        if (ks < KSTEPS - 1) {
            XLOAD(ks + 1);
            #pragma unroll
            for (int nf = 0; nf < 4; ++nf) bhv[nxt][nf] = *(const bf16x8*)(whk1 + nf * 512);
        }
        SB();
        // MFMA GA: Q frags nf 0..3, split 3x
        #pragma unroll
        for (int nf = 0; nf < 4; ++nf) {
            acc[0][nf] = mfma(ahq[par][0], bhv[par][nf], acc[0][nf]);
            acc[1][nf] = mfma(ahq[par][1], bhv[par][nf], acc[1][nf]);
            acc[0][nf] = mfma(ahq[par][0], blv[par][nf], acc[0][nf]);
            acc[1][nf] = mfma(ahq[par][1], blv[par][nf], acc[1][nf]);
            acc[0][nf] = mfma(alq[par][0], bhv[par][nf], acc[0][nf]);
            acc[1][nf] = mfma(alq[par][1], bhv[par][nf], acc[1][nf]);
        }
        SB();
        // S_B: GA-lo + GB-hi (ks+1)
        if (ks < KSTEPS - 1) {
            #pragma unroll
            for (int nf = 0; nf < 4; ++nf) blv[nxt][nf] = *(const bf16x8*)(wlk1 + nf * 512);
            #pragma unroll
            for (int nf = 4; nf < 8; ++nf) bhv[nxt][nf] = *(const bf16x8*)(whk1 + nf * 512);
        }
        SB();
        // MFMA GB: K frags nf 4..7, split 3x
        #pragma unroll
        for (int nf = 4; nf < 8; ++nf) {
            acc[0][nf] = mfma(ahq[par][0], bhv[par][nf], acc[0][nf]);
            acc[1][nf] = mfma(ahq[par][1], bhv[par][nf], acc[1][nf]);
            acc[0][nf] = mfma(ahq[par][0], blv[par][nf], acc[0][nf]);
            acc[1][nf] = mfma(ahq[par][1], blv[par][nf], acc[1][nf]);
            acc[0][nf] = mfma(alq[par][0], bhv[par][nf], acc[0][nf]);
            acc[1][nf] = mfma(alq[par][1], bhv[par][nf], acc[1][nf]);
        }
        SB();
        // S_C: GB-lo + GC-hi (ks+1) + split of x(ks+1)
        if (ks < KSTEPS - 1) {
            #pragma unroll
            for (int nf = 4; nf < 8;  ++nf) blv[nxt][nf] = *(const bf16x8*)(wlk1 + nf * 512);
            #pragma unroll
            for (int nf = 8; nf < 12; ++nf) bhv[nxt][nf] = *(const bf16x8*)(whk1 + nf * 512);
            SPLIT_A(nxt);
        }
        SB();
        // MFMA GC: V frags nf 8..11, plain
        #pragma unroll
        for (int nf = 8; nf < 12; ++nf) {
            acc[0][nf] = mfma(ahq[par][0], bhv[par][nf], acc[0][nf]);
            acc[1][nf] = mfma(ahq[par][1], bhv[par][nf], acc[1][nf]);
        }
        SB();
    }

    // ---- epilogue: K -> Kh/Kl (split), V -> Vt (transposed), swizzled ----
    #pragma unroll
    for (int mf = 0; mf < 2; ++mf)
    #pragma unroll
    for (int f = 0; f < 4; ++f)
    #pragma unroll
    for (int rr = 0; rr < 4; ++rr) {
        int q = m0w + mf * 16 + 4 * g + rr;
        int d = f * 16 + r16;
        int ek = q * 64 + (((d >> 3) ^ (q & 7)) << 3) + (d & 7);
        float kv = acc[mf][4 + f][rr];
        bf16_t khi = (bf16_t)kv;
        Kh[ek] = __builtin_bit_cast(u16, khi);
        Kl[ek] = f2b(kv - (float)khi);
        Vt[d * 256 + (((q >> 3) ^ (d & 7)) << 3) + (q & 7)] = f2b(acc[mf][8 + f][rr]);
    }

    // ---- Q bounce: C-layout -> A-fragments via per-wave LDS, 2 passes ----
    u16* myQb = Qb + wid * 2560;
    bf16x8 aqh[2][2], aql[2][2];
    #pragma unroll
    for (int mf = 0; mf < 2; ++mf)
    #pragma unroll
    for (int f = 0; f < 4; ++f)
    #pragma unroll
    for (int rr = 0; rr < 4; ++rr) {
        int r = mf * 16 + 4 * g + rr;
        int c = f * 16 + r16;
        myQb[r * 64 + (((c >> 3) ^ (r & 7)) << 3) + (c & 7)] = f2b(acc[mf][f][rr]);
    }
    #pragma unroll
    for (int mf = 0; mf < 2; ++mf)
    #pragma unroll
    for (int k2 = 0; k2 < 2; ++k2) {
        int r = mf * 16 + r16;
        aqh[mf][k2] = *(const bf16x8*)&myQb[r * 64 + (((k2 * 4 + g) ^ (r & 7)) << 3)];
    }
    SB();   // keep lo-pass writes after hi-pass reads
    #pragma unroll
    for (int mf = 0; mf < 2; ++mf)
    #pragma unroll
    for (int f = 0; f < 4; ++f)
    #pragma unroll
    for (int rr = 0; rr < 4; ++rr) {
        int r = mf * 16 + 4 * g + rr;
        int c = f * 16 + r16;
        float v = acc[mf][f][rr];
        bf16_t hi = (bf16_t)v;
        myQb[r * 64 + (((c >> 3) ^ (r & 7)) << 3) + (c & 7)] = f2b(v - (float)hi);
    }
    #pragma unroll
    for (int mf = 0; mf < 2; ++mf)
    #pragma unroll
    for (int k2 = 0; k2 < 2; ++k2) {
        int r = mf * 16 + r16;
        aql[mf][k2] = *(const bf16x8*)&myQb[r * 64 + (((k2 * 4 + g) ^ (r & 7)) << 3)];
    }

    __syncthreads();   // Kh/Kl/Vt now visible block-wide

    // ---------------- phase 2: S = Q K^T (split, 3 MFMA), prefetch 1 nf ----
    f32x4 S[2][16];
    #pragma unroll
    for (int mf = 0; mf < 2; ++mf)
        #pragma unroll
        for (int nf = 0; nf < 16; ++nf) S[mf][nf] = f32x4{0.f,0.f,0.f,0.f};

    bf16x8 khv[2][2], klv[2][2];
    {   // prefetch nf=0
        int q = r16;
        #pragma unroll
        for (int k2 = 0; k2 < 2; ++k2) {
            int e = q * 64 + (((k2 * 4 + g) ^ (q & 7)) << 3);
            khv[0][k2] = *(const bf16x8*)&Kh[e];
            klv[0][k2] = *(const bf16x8*)&Kl[e];
        }
    }
    #pragma unroll
    for (int nf = 0; nf < 16; ++nf) {
        const int par = nf & 1, nxt = par ^ 1;
        if (nf < 15) {
            int q = (nf + 1) * 16 + r16;
            #pragma unroll
            for (int k2 = 0; k2 < 2; ++k2) {
                int e = q * 64 + (((k2 * 4 + g) ^ (q & 7)) << 3);
                khv[nxt][k2] = *(const bf16x8*)&Kh[e];
                klv[nxt][k2] = *(const bf16x8*)&Kl[e];
            }
        }
        SB();
        __builtin_amdgcn_s_setprio(1);
        #pragma unroll
        for (int k2 = 0; k2 < 2; ++k2) {
            S[0][nf] = mfma(aqh[0][k2], khv[par][k2], S[0][nf]);
            S[1][nf] = mfma(aqh[1][k2], khv[par][k2], S[1][nf]);
            S[0][nf] = mfma(aqh[0][k2], klv[par][k2], S[0][nf]);
            S[1][nf] = mfma(aqh[1][k2], klv[par][k2], S[1][nf]);
            S[0][nf] = mfma(aql[0][k2], khv[par][k2], S[0][nf]);
            S[1][nf] = mfma(aql[1][k2], khv[par][k2], S[1][nf]);
        }
        __builtin_amdgcn_s_setprio(0);
        SB();
    }

    // ---------------- softmax (rows lane-spread over 16 lanes) -------------
    float inv_[2][4];
    #pragma unroll
    for (int mf = 0; mf < 2; ++mf) {
        float mrow[4] = {-1e30f,-1e30f,-1e30f,-1e30f};
        #pragma unroll
        for (int nf = 0; nf < 16; ++nf)
            #pragma unroll
            for (int rr = 0; rr < 4; ++rr) mrow[rr] = fmaxf(mrow[rr], S[mf][nf][rr]);
        #pragma unroll
        for (int mask = 1; mask < 16; mask <<= 1)
            #pragma unroll
            for (int rr = 0; rr < 4; ++rr) mrow[rr] = fmaxf(mrow[rr], __shfl_xor(mrow[rr], mask, 64));
        float ssum[4] = {0.f,0.f,0.f,0.f};
        #pragma unroll
        for (int nf = 0; nf < 16; ++nf)
            #pragma unroll
            for (int rr = 0; rr < 4; ++rr) {
                float pv = __expf((S[mf][nf][rr] - mrow[rr]) * 64.0f);  // scale = D
                S[mf][nf][rr] = pv;
                ssum[rr] += pv;
            }
        #pragma unroll
        for (int mask = 1; mask < 16; mask <<= 1)
            #pragma unroll
            for (int rr = 0; rr < 4; ++rr) ssum[rr] += __shfl_xor(ssum[rr], mask, 64);
        #pragma unroll
        for (int rr = 0; rr < 4; ++rr) inv_[mf][rr] = 1.0f / ssum[rr];
    }

    // ---------------- phase 3: O = P V (double-buffered bounce, stride 40) -
    f32x4 O[2][4];
    #pragma unroll
    for (int mf = 0; mf < 2; ++mf)
        #pragma unroll
        for (int f = 0; f < 4; ++f) O[mf][f] = f32x4{0.f,0.f,0.f,0.f};

    bf16x8 bvv[2][4];
    #pragma unroll
    for (int f = 0; f < 4; ++f) {   // prefetch t=0
        int d = f * 16 + r16;
        bvv[0][f] = *(const bf16x8*)&Vt[d * 256 + ((((8 * g) >> 3) ^ (d & 7)) << 3)];
    }
    #pragma unroll
    for (int t = 0; t < 8; ++t) {
        const int par = t & 1, nxt = par ^ 1;
        if (t < 7) {
            #pragma unroll
            for (int f = 0; f < 4; ++f) {
                int d = f * 16 + r16;
                bvv[nxt][f] = *(const bf16x8*)&Vt[d * 256 + (((((t + 1) * 32 + 8 * g) >> 3) ^ (d & 7)) << 3)];
            }
        }
        u16* pb = myQb + par * 1280;             // [32][PB_STRIDE]
        #pragma unroll
        for (int mf = 0; mf < 2; ++mf)
        #pragma unroll
        for (int tt = 0; tt < 2; ++tt) {
            int nf = 2 * t + tt;
            #pragma unroll
            for (int rr = 0; rr < 4; ++rr)
                pb[(mf * 16 + 4 * g + rr) * PB_STRIDE + tt * 16 + r16] = f2b(S[mf][nf][rr] * inv_[mf][rr]);
        }
        bf16x8 ap0 = *(const bf16x8*)&pb[(r16) * PB_STRIDE + 8 * g];
        bf16x8 ap1 = *(const bf16x8*)&pb[(16 + r16) * PB_STRIDE + 8 * g];
        __builtin_amdgcn_s_setprio(1);
        #pragma unroll
        for (int f = 0; f < 4; ++f) {
            O[0][f] = mfma(ap0, bvv[par][f], O[0][f]);
            O[1][f] = mfma(ap1, bvv[par][f], O[1][f]);
        }
        __builtin_amdgcn_s_setprio(0);
    }

    #pragma unroll
    for (int mf = 0; mf < 2; ++mf)
    #pragma unroll
    for (int f = 0; f < 4; ++f)
    #pragma unroll
    for (int rr = 0; rr < 4; ++rr)
        attn[(row0 + m0w + mf * 16 + 4 * g + rr) * C_ + h * 64 + f * 16 + r16] = f2b(O[mf][f][rr]);
}

// ---------------------------------------------------------------------------
// proj: attn(65536x384 bf16) @ w_proj(384x384) + bias -> f32 out.
// ---------------------------------------------------------------------------
__global__ __launch_bounds__(256, 2) void proj_kernel(
    const u16* __restrict__ attn, const u16* __restrict__ wPt,
    const float* __restrict__ bias, float* __restrict__ out)
{
    __shared__ alignas(16) u16 As[128*32];
    __shared__ alignas(16) u16 Bs[128*32];

    const int tid = threadIdx.x;
    const int lane = tid & 63, wid = tid >> 6;
    const int wr = wid >> 1, wc = wid & 1;
    const int g = lane >> 4, r16 = lane & 15;
    const int m0 = blockIdx.x * 128;
    const int n0 = blockIdx.y * 128;

    f32x4 acc[4][4];
    for (int i = 0; i < 4; i++) for (int j = 0; j < 4; j++) acc[i][j] = f32x4{0.f,0.f,0.f,0.f};

    for (int kt = 0; kt < C_; kt += 32) {
        for (int r = 0; r < 4; ++r) {
            int i = tid + 256*r;
            int mm = i >> 3;
            int kk = (i & 7) << 2;
            u16x4 v = *(const u16x4*)&attn[(size_t)(m0+mm)*C_ + kt + kk];
            int e = mm*32 + (((kk>>3) ^ ((mm>>1)&3))<<3) + (kk&7);
            *(u16x4*)&As[e] = v;
        }
        for (int r = 0; r < 4; ++r) {
            int i = tid + 256*r;
            int nn = i >> 3;
            int kk = (i & 7) << 2;
            u16x4 v = *(const u16x4*)&wPt[(size_t)(n0+nn)*C_ + kt + kk];
            int e = nn*32 + (((kk>>3) ^ ((nn>>1)&3))<<3) + (kk&7);
            *(u16x4*)&Bs[e] = v;
        }
        __syncthreads();

        bf16x8 a[4], b[4];
        for (int i = 0; i < 4; i++) {
            int row = wr*64 + i*16 + r16;
            a[i] = *(const bf16x8*)&As[row*32 + ((g ^ ((row>>1)&3))<<3)];
        }
        for (int j = 0; j < 4; j++) {
            int n = wc*64 + j*16 + r16;
            b[j] = *(const bf16x8*)&Bs[n*32 + ((g ^ ((n>>1)&3))<<3)];
        }
        for (int i = 0; i < 4; i++) for (int j = 0; j < 4; j++)
            acc[i][j] = mfma(a[i], b[j], acc[i][j]);
        __syncthreads();
    }

    for (int i = 0; i < 4; i++) for (int j = 0; j < 4; j++) for (int rr = 0; rr < 4; rr++) {
        size_t row = m0 + wr*64 + i*16 + g*4 + rr;
        int col = n0 + wc*64 + j*16 + r16;
        out[row*C_ + col] = acc[i][j][rr] + bias[col];
    }
}

// ---------------------------------------------------------------------------
extern "C" void kernel_launch(void* const* d_in, const int* in_sizes, int n_in,
                              void* d_out, int out_size, void* d_ws, size_t ws_size,
                              hipStream_t stream)
{
    const float* x      = (const float*)d_in[0];
    const float* w_qkv  = (const float*)d_in[1];
    const float* w_proj = (const float*)d_in[2];
    const float* b_proj = (const float*)d_in[3];
    float* out = (float*)d_out;

    u16* ws = (u16*)d_ws;
    u16* attnb = ws;                                  // 65536*384 u16 = 50 MB
    size_t off = (size_t)M_TOTAL * C_;
    u16* Wfh = ws + off; off += (size_t)H_ * WF_HSTRIDE;
    u16* Wfl = ws + off; off += (size_t)H_ * WF_HSTRIDE;
    u16* wPt = ws + off; off += (size_t)C_ * C_;

    hipFuncSetAttribute((const void*)fused_attn,
                        hipFuncAttributeMaxDynamicSharedMemorySize, FUSED_LDS);

    int prep_n = H_ * KSTEPS * NFRAG * 64 + C_ * C_;
    prep_w<<<dim3((prep_n + 255) / 256), 256, 0, stream>>>(w_qkv, w_proj, Wfh, Wfl, wPt);
    fused_attn<<<dim3(NBLK), 512, FUSED_LDS, stream>>>(x, Wfh, Wfl, attnb);
    proj_kernel<<<dim3(M_TOTAL / 128, C_ / 128), 256, 0, stream>>>(attnb, wPt, b_proj, out);
}

// Round 5
// 265.589 us; speedup vs baseline: 2.0291x; 1.0591x over previous
//
#include <hip/hip_runtime.h>

typedef __bf16 bf16_t;
typedef __bf16 bf16x8 __attribute__((ext_vector_type(8)));
typedef float f32x4 __attribute__((ext_vector_type(4)));
typedef unsigned short u16;
typedef unsigned short u16x4 __attribute__((ext_vector_type(4)));
typedef unsigned int u32;

#define B_ 4
#define N_ 64
#define P_ 256
#define C_ 384
#define H_ 6
#define D_ 64
#define M_TOTAL 65536
#define NQKV 1152
#define KSTEPS 12                     // 384/32
#define NBLK (H_*B_*N_)               // 1536 = 8 XCDs * 192
#define WKS_BYTES 24576               // packed weights per (h,ks): 12 hi + 12 lo frags x 1KB
#define WKS_U16   12288
// LDS: Kh 32K + Kl 32K + Vt 32K + 8 waves * 5120B bounce = 136 KB
// (weight stage buffers 2 x 24KB live inside Kh/Kl region during phase 1)
#define FUSED_LDS 139264
#define PB_STRIDE 40                  // P-bounce row stride (u16)
#define SB() __builtin_amdgcn_sched_barrier(0)

#define GLOAD_LDS16(g, l) __builtin_amdgcn_global_load_lds( \
    (const __attribute__((address_space(1))) void*)(g), \
    (__attribute__((address_space(3))) void*)(l), 16, 0, 0)

__device__ __forceinline__ u16 f2b(float f){ return __builtin_bit_cast(u16, (bf16_t)f); }
__device__ __forceinline__ f32x4 mfma(bf16x8 a, bf16x8 b, f32x4 c){
    return __builtin_amdgcn_mfma_f32_16x16x32_bf16(a, b, c, 0, 0, 0);
}

// ---------------------------------------------------------------------------
// prep: (a) packed per-(h,ks) weight blocks: [12 hi frags | 12 lo frags],
//           each frag = 64 lanes x 8 u16 (contiguous 24KB per block so the
//           global_load_lds destination is exactly linear)
//       (b) w_proj^T bf16 for the proj GEMM
// ---------------------------------------------------------------------------
__global__ __launch_bounds__(256) void prep_w(
    const float* __restrict__ wqkv, const float* __restrict__ wproj,
    u16* __restrict__ Wpk, u16* __restrict__ wPt)
{
    int i = blockIdx.x * 256 + threadIdx.x;
    const int NSLOT = H_ * KSTEPS * 12 * 64;   // 55296
    if (i < NSLOT) {
        int lane = i & 63;
        int frag = i >> 6;
        int nf = frag % 12;
        int ks = (frag / 12) % KSTEPS;
        int h  = frag / (12 * KSTEPS);
        int part = nf >> 2;                        // 0=Q 1=K 2=V
        int nh   = (nf & 3) * 16 + (lane & 15);    // 0..63 within head
        int col  = part * C_ + h * 64 + nh;        // col in w_qkv
        int k0   = ks * 32 + (lane >> 4) * 8;
        size_t base = (size_t)(h * KSTEPS + ks) * WKS_U16 + nf * 512 + lane * 8;
        #pragma unroll
        for (int e = 0; e < 8; ++e) {
            float w = wqkv[(size_t)(k0 + e) * NQKV + col];
            bf16_t hi = (bf16_t)w;
            Wpk[base + e]        = __builtin_bit_cast(u16, hi);
            Wpk[base + 6144 + e] = f2b(w - (float)hi);   // lo plane (V-lo stored, unused)
        }
    }
    int j = i - NSLOT;
    if (j >= 0 && j < C_ * C_) {
        int k = j / C_, n = j % C_;
        wPt[(size_t)n * C_ + k] = f2b(wproj[j]);
    }
}

// ---------------------------------------------------------------------------
// fused per-(h, b*n) kernel: QKV projection (split bf16) + attention.
// 512 threads = 8 waves; wave owns 32 q-rows. Weights staged per k-step into
// LDS (global_load_lds, double-buffered); __launch_bounds__(512,2) grants the
// 256-VGPR budget so S and prefetch operands stay in registers (no spill).
// ---------------------------------------------------------------------------
__global__ __launch_bounds__(512, 2) void fused_attn(
    const float* __restrict__ x, const u16* __restrict__ Wpk,
    u16* __restrict__ attn)
{
    extern __shared__ u16 sm[];
    u16* Kh = sm;              // [256][64] swizzled, 32 KB   (epilogue onward)
    u16* Kl = sm + 16384;      // 32 KB                        (epilogue onward)
    u16* Vt = sm + 32768;      // [64][256] swizzled, 32 KB
    u16* Qb = sm + 49152;      // 8 waves x 2560 u16 (Q bounce + P double-buffer)
    // weight stage buffers (phase 1 only): sm[0..12288) and sm[12288..24576)

    const int tid  = threadIdx.x;
    const int lane = tid & 63, wid = tid >> 6;
    const int g = lane >> 4, r16 = lane & 15;

    // XCD-chunk swizzle (bijective: 1536 = 8 * 192)
    const int p = blockIdx.x;
    const int logical = (p & 7) * (NBLK / 8) + (p >> 3);
    const int h  = logical % H_;
    const int bn = logical / H_;
    const size_t row0 = (size_t)bn * P_;
    const int m0w = wid * 32;

    // ---------------- phase 1: [Q|K|V] = X_slab @ W3head, split bf16 -------
    f32x4 acc[2][12];
    #pragma unroll
    for (int mf = 0; mf < 2; ++mf)
        #pragma unroll
        for (int nf = 0; nf < 12; ++nf) acc[mf][nf] = f32x4{0.f,0.f,0.f,0.f};

    const float* xr0 = x + (row0 + m0w + r16) * C_;
    const float* xr1 = xr0 + 16 * C_;
    const char* wbase = (const char*)Wpk + (size_t)h * (KSTEPS * WKS_BYTES);

#define STAGE(ks_, par_) do { \
    const char* _gp = wbase + (size_t)(ks_) * WKS_BYTES; \
    char* _lp = (char*)(sm + (par_) * WKS_U16); \
    GLOAD_LDS16(_gp + tid * 16,          _lp + tid * 16); \
    GLOAD_LDS16(_gp + 8192 + tid * 16,   _lp + 8192 + tid * 16); \
    GLOAD_LDS16(_gp + 16384 + tid * 16,  _lp + 16384 + tid * 16); \
} while (0)

    f32x4 xr[2][4];
#define XLOAD(ks_, par_) do { \
    const float* _xp0 = xr0 + (ks_) * 32 + 8 * g; \
    const float* _xp1 = xr1 + (ks_) * 32 + 8 * g; \
    xr[par_][0] = *(const f32x4*)_xp0; xr[par_][1] = *(const f32x4*)(_xp0 + 4); \
    xr[par_][2] = *(const f32x4*)_xp1; xr[par_][3] = *(const f32x4*)(_xp1 + 4); \
} while (0)

    bf16x8 ah[2], al[2];
#define SPLIT_A(par_) do { \
    _Pragma("unroll") \
    for (int e = 0; e < 4; ++e) { \
        bf16_t h0 = (bf16_t)xr[par_][0][e], h1 = (bf16_t)xr[par_][1][e]; \
        ah[0][e]   = h0; al[0][e]   = (bf16_t)(xr[par_][0][e] - (float)h0); \
        ah[0][4+e] = h1; al[0][4+e] = (bf16_t)(xr[par_][1][e] - (float)h1); \
        bf16_t h2 = (bf16_t)xr[par_][2][e], h3 = (bf16_t)xr[par_][3][e]; \
        ah[1][e]   = h2; al[1][e]   = (bf16_t)(xr[par_][2][e] - (float)h2); \
        ah[1][4+e] = h3; al[1][4+e] = (bf16_t)(xr[par_][3][e] - (float)h3); \
    } } while (0)

    // prologue: stage ks=0 and load x(0)
    STAGE(0, 0);
    XLOAD(0, 0);
    __syncthreads();   // stage(0) visible to all waves

    #pragma unroll
    for (int ks = 0; ks < KSTEPS; ++ks) {
        const int par = ks & 1, nxt = par ^ 1;
        if (ks < KSTEPS - 1) {
            STAGE(ks + 1, nxt);      // async, drains at this iteration's barrier
            XLOAD(ks + 1, nxt);
        }
        SPLIT_A(par);
        const u16* stg = sm + par * WKS_U16;
        #pragma unroll
        for (int nf = 0; nf < 8; ++nf) {    // Q,K: split 3x
            bf16x8 bh = *(const bf16x8*)&stg[nf * 512 + lane * 8];
            bf16x8 bl = *(const bf16x8*)&stg[6144 + nf * 512 + lane * 8];
            acc[0][nf] = mfma(ah[0], bh, acc[0][nf]);
            acc[1][nf] = mfma(ah[1], bh, acc[1][nf]);
            acc[0][nf] = mfma(ah[0], bl, acc[0][nf]);
            acc[1][nf] = mfma(ah[1], bl, acc[1][nf]);
            acc[0][nf] = mfma(al[0], bh, acc[0][nf]);
            acc[1][nf] = mfma(al[1], bh, acc[1][nf]);
        }
        #pragma unroll
        for (int nf = 8; nf < 12; ++nf) {   // V: plain
            bf16x8 bh = *(const bf16x8*)&stg[nf * 512 + lane * 8];
            acc[0][nf] = mfma(ah[0], bh, acc[0][nf]);
            acc[1][nf] = mfma(ah[1], bh, acc[1][nf]);
        }
        __syncthreads();   // stage(ks+1) complete + all waves done with stg[par]
    }

    // ---- epilogue: K -> Kh/Kl (split), V -> Vt (transposed), swizzled ----
    // (stage buffers are dead now; Kh/Kl region is safe to write)
    #pragma unroll
    for (int mf = 0; mf < 2; ++mf)
    #pragma unroll
    for (int f = 0; f < 4; ++f)
    #pragma unroll
    for (int rr = 0; rr < 4; ++rr) {
        int q = m0w + mf * 16 + 4 * g + rr;
        int d = f * 16 + r16;
        int ek = q * 64 + (((d >> 3) ^ (q & 7)) << 3) + (d & 7);
        float kv = acc[mf][4 + f][rr];
        bf16_t khi = (bf16_t)kv;
        Kh[ek] = __builtin_bit_cast(u16, khi);
        Kl[ek] = f2b(kv - (float)khi);
        Vt[d * 256 + (((q >> 3) ^ (d & 7)) << 3) + (q & 7)] = f2b(acc[mf][8 + f][rr]);
    }

    // ---- Q bounce: C-layout -> A-fragments via per-wave LDS, 2 passes ----
    u16* myQb = Qb + wid * 2560;
    bf16x8 aqh[2][2], aql[2][2];
    #pragma unroll
    for (int mf = 0; mf < 2; ++mf)
    #pragma unroll
    for (int f = 0; f < 4; ++f)
    #pragma unroll
    for (int rr = 0; rr < 4; ++rr) {
        int r = mf * 16 + 4 * g + rr;
        int c = f * 16 + r16;
        myQb[r * 64 + (((c >> 3) ^ (r & 7)) << 3) + (c & 7)] = f2b(acc[mf][f][rr]);
    }
    #pragma unroll
    for (int mf = 0; mf < 2; ++mf)
    #pragma unroll
    for (int k2 = 0; k2 < 2; ++k2) {
        int r = mf * 16 + r16;
        aqh[mf][k2] = *(const bf16x8*)&myQb[r * 64 + (((k2 * 4 + g) ^ (r & 7)) << 3)];
    }
    SB();   // keep lo-pass writes after hi-pass reads
    #pragma unroll
    for (int mf = 0; mf < 2; ++mf)
    #pragma unroll
    for (int f = 0; f < 4; ++f)
    #pragma unroll
    for (int rr = 0; rr < 4; ++rr) {
        int r = mf * 16 + 4 * g + rr;
        int c = f * 16 + r16;
        float v = acc[mf][f][rr];
        bf16_t hi = (bf16_t)v;
        myQb[r * 64 + (((c >> 3) ^ (r & 7)) << 3) + (c & 7)] = f2b(v - (float)hi);
    }
    #pragma unroll
    for (int mf = 0; mf < 2; ++mf)
    #pragma unroll
    for (int k2 = 0; k2 < 2; ++k2) {
        int r = mf * 16 + r16;
        aql[mf][k2] = *(const bf16x8*)&myQb[r * 64 + (((k2 * 4 + g) ^ (r & 7)) << 3)];
    }

    __syncthreads();   // Kh/Kl/Vt now visible block-wide

    // ---------------- phase 2: S = Q K^T (split, 3 MFMA), prefetch 1 nf ----
    f32x4 S[2][16];
    #pragma unroll
    for (int mf = 0; mf < 2; ++mf)
        #pragma unroll
        for (int nf = 0; nf < 16; ++nf) S[mf][nf] = f32x4{0.f,0.f,0.f,0.f};

    bf16x8 khv[2][2], klv[2][2];
    {   // prefetch nf=0
        int q = r16;
        #pragma unroll
        for (int k2 = 0; k2 < 2; ++k2) {
            int e = q * 64 + (((k2 * 4 + g) ^ (q & 7)) << 3);
            khv[0][k2] = *(const bf16x8*)&Kh[e];
            klv[0][k2] = *(const bf16x8*)&Kl[e];
        }
    }
    #pragma unroll
    for (int nf = 0; nf < 16; ++nf) {
        const int par = nf & 1, nxt = par ^ 1;
        if (nf < 15) {
            int q = (nf + 1) * 16 + r16;
            #pragma unroll
            for (int k2 = 0; k2 < 2; ++k2) {
                int e = q * 64 + (((k2 * 4 + g) ^ (q & 7)) << 3);
                khv[nxt][k2] = *(const bf16x8*)&Kh[e];
                klv[nxt][k2] = *(const bf16x8*)&Kl[e];
            }
        }
        SB();
        __builtin_amdgcn_s_setprio(1);
        #pragma unroll
        for (int k2 = 0; k2 < 2; ++k2) {
            S[0][nf] = mfma(aqh[0][k2], khv[par][k2], S[0][nf]);
            S[1][nf] = mfma(aqh[1][k2], khv[par][k2], S[1][nf]);
            S[0][nf] = mfma(aqh[0][k2], klv[par][k2], S[0][nf]);
            S[1][nf] = mfma(aqh[1][k2], klv[par][k2], S[1][nf]);
            S[0][nf] = mfma(aql[0][k2], khv[par][k2], S[0][nf]);
            S[1][nf] = mfma(aql[1][k2], khv[par][k2], S[1][nf]);
        }
        __builtin_amdgcn_s_setprio(0);
        SB();
    }

    // ---------------- softmax (rows lane-spread over 16 lanes) -------------
    float inv_[2][4];
    #pragma unroll
    for (int mf = 0; mf < 2; ++mf) {
        float mrow[4] = {-1e30f,-1e30f,-1e30f,-1e30f};
        #pragma unroll
        for (int nf = 0; nf < 16; ++nf)
            #pragma unroll
            for (int rr = 0; rr < 4; ++rr) mrow[rr] = fmaxf(mrow[rr], S[mf][nf][rr]);
        #pragma unroll
        for (int mask = 1; mask < 16; mask <<= 1)
            #pragma unroll
            for (int rr = 0; rr < 4; ++rr) mrow[rr] = fmaxf(mrow[rr], __shfl_xor(mrow[rr], mask, 64));
        float ssum[4] = {0.f,0.f,0.f,0.f};
        #pragma unroll
        for (int nf = 0; nf < 16; ++nf)
            #pragma unroll
            for (int rr = 0; rr < 4; ++rr) {
                float pv = __expf((S[mf][nf][rr] - mrow[rr]) * 64.0f);  // scale = D
                S[mf][nf][rr] = pv;
                ssum[rr] += pv;
            }
        #pragma unroll
        for (int mask = 1; mask < 16; mask <<= 1)
            #pragma unroll
            for (int rr = 0; rr < 4; ++rr) ssum[rr] += __shfl_xor(ssum[rr], mask, 64);
        #pragma unroll
        for (int rr = 0; rr < 4; ++rr) inv_[mf][rr] = 1.0f / ssum[rr];
    }

    // ---------------- phase 3: O = P V (double-buffered bounce, stride 40) -
    f32x4 O[2][4];
    #pragma unroll
    for (int mf = 0; mf < 2; ++mf)
        #pragma unroll
        for (int f = 0; f < 4; ++f) O[mf][f] = f32x4{0.f,0.f,0.f,0.f};

    bf16x8 bvv[2][4];
    #pragma unroll
    for (int f = 0; f < 4; ++f) {   // prefetch t=0
        int d = f * 16 + r16;
        bvv[0][f] = *(const bf16x8*)&Vt[d * 256 + ((((8 * g) >> 3) ^ (d & 7)) << 3)];
    }
    #pragma unroll
    for (int t = 0; t < 8; ++t) {
        const int par = t & 1, nxt = par ^ 1;
        if (t < 7) {
            #pragma unroll
            for (int f = 0; f < 4; ++f) {
                int d = f * 16 + r16;
                bvv[nxt][f] = *(const bf16x8*)&Vt[d * 256 + (((((t + 1) * 32 + 8 * g) >> 3) ^ (d & 7)) << 3)];
            }
        }
        u16* pb = myQb + par * 1280;             // [32][PB_STRIDE]
        #pragma unroll
        for (int mf = 0; mf < 2; ++mf)
        #pragma unroll
        for (int tt = 0; tt < 2; ++tt) {
            int nf = 2 * t + tt;
            #pragma unroll
            for (int rr = 0; rr < 4; ++rr)
                pb[(mf * 16 + 4 * g + rr) * PB_STRIDE + tt * 16 + r16] = f2b(S[mf][nf][rr] * inv_[mf][rr]);
        }
        bf16x8 ap0 = *(const bf16x8*)&pb[(r16) * PB_STRIDE + 8 * g];
        bf16x8 ap1 = *(const bf16x8*)&pb[(16 + r16) * PB_STRIDE + 8 * g];
        __builtin_amdgcn_s_setprio(1);
        #pragma unroll
        for (int f = 0; f < 4; ++f) {
            O[0][f] = mfma(ap0, bvv[par][f], O[0][f]);
            O[1][f] = mfma(ap1, bvv[par][f], O[1][f]);
        }
        __builtin_amdgcn_s_setprio(0);
    }

    #pragma unroll
    for (int mf = 0; mf < 2; ++mf)
    #pragma unroll
    for (int f = 0; f < 4; ++f)
    #pragma unroll
    for (int rr = 0; rr < 4; ++rr)
        attn[(row0 + m0w + mf * 16 + 4 * g + rr) * C_ + h * 64 + f * 16 + r16] = f2b(O[mf][f][rr]);
}

// ---------------------------------------------------------------------------
// proj: attn(65536x384 bf16) @ w_proj(384x384) + bias -> f32 out.
// ---------------------------------------------------------------------------
__global__ __launch_bounds__(256, 2) void proj_kernel(
    const u16* __restrict__ attn, const u16* __restrict__ wPt,
    const float* __restrict__ bias, float* __restrict__ out)
{
    __shared__ alignas(16) u16 As[128*32];
    __shared__ alignas(16) u16 Bs[128*32];

    const int tid = threadIdx.x;
    const int lane = tid & 63, wid = tid >> 6;
    const int wr = wid >> 1, wc = wid & 1;
    const int g = lane >> 4, r16 = lane & 15;
    const int m0 = blockIdx.x * 128;
    const int n0 = blockIdx.y * 128;

    f32x4 acc[4][4];
    for (int i = 0; i < 4; i++) for (int j = 0; j < 4; j++) acc[i][j] = f32x4{0.f,0.f,0.f,0.f};

    for (int kt = 0; kt < C_; kt += 32) {
        for (int r = 0; r < 4; ++r) {
            int i = tid + 256*r;
            int mm = i >> 3;
            int kk = (i & 7) << 2;
            u16x4 v = *(const u16x4*)&attn[(size_t)(m0+mm)*C_ + kt + kk];
            int e = mm*32 + (((kk>>3) ^ ((mm>>1)&3))<<3) + (kk&7);
            *(u16x4*)&As[e] = v;
        }
        for (int r = 0; r < 4; ++r) {
            int i = tid + 256*r;
            int nn = i >> 3;
            int kk = (i & 7) << 2;
            u16x4 v = *(const u16x4*)&wPt[(size_t)(n0+nn)*C_ + kt + kk];
            int e = nn*32 + (((kk>>3) ^ ((nn>>1)&3))<<3) + (kk&7);
            *(u16x4*)&Bs[e] = v;
        }
        __syncthreads();

        bf16x8 a[4], b[4];
        for (int i = 0; i < 4; i++) {
            int row = wr*64 + i*16 + r16;
            a[i] = *(const bf16x8*)&As[row*32 + ((g ^ ((row>>1)&3))<<3)];
        }
        for (int j = 0; j < 4; j++) {
            int n = wc*64 + j*16 + r16;
            b[j] = *(const bf16x8*)&Bs[n*32 + ((g ^ ((n>>1)&3))<<3)];
        }
        for (int i = 0; i < 4; i++) for (int j = 0; j < 4; j++)
            acc[i][j] = mfma(a[i], b[j], acc[i][j]);
        __syncthreads();
    }

    for (int i = 0; i < 4; i++) for (int j = 0; j < 4; j++) for (int rr = 0; rr < 4; rr++) {
        size_t row = m0 + wr*64 + i*16 + g*4 + rr;
        int col = n0 + wc*64 + j*16 + r16;
        out[row*C_ + col] = acc[i][j][rr] + bias[col];
    }
}

// ---------------------------------------------------------------------------
extern "C" void kernel_launch(void* const* d_in, const int* in_sizes, int n_in,
                              void* d_out, int out_size, void* d_ws, size_t ws_size,
                              hipStream_t stream)
{
    const float* x      = (const float*)d_in[0];
    const float* w_qkv  = (const float*)d_in[1];
    const float* w_proj = (const float*)d_in[2];
    const float* b_proj = (const float*)d_in[3];
    float* out = (float*)d_out;

    u16* ws = (u16*)d_ws;
    u16* attnb = ws;                                  // 65536*384 u16 = 50 MB
    size_t off = (size_t)M_TOTAL * C_;
    u16* Wpk = ws + off; off += (size_t)H_ * KSTEPS * WKS_U16;
    u16* wPt = ws + off; off += (size_t)C_ * C_;

    hipFuncSetAttribute((const void*)fused_attn,
                        hipFuncAttributeMaxDynamicSharedMemorySize, FUSED_LDS);

    int prep_n = H_ * KSTEPS * 12 * 64 + C_ * C_;
    prep_w<<<dim3((prep_n + 255) / 256), 256, 0, stream>>>(w_qkv, w_proj, Wpk, wPt);
    fused_attn<<<dim3(NBLK), 512, FUSED_LDS, stream>>>(x, Wpk, attnb);
    proj_kernel<<<dim3(M_TOTAL / 128, C_ / 128), 256, 0, stream>>>(attnb, wPt, b_proj, out);
}

// Round 6
// 248.642 us; speedup vs baseline: 2.1674x; 1.0682x over previous
//
#include <hip/hip_runtime.h>

typedef __bf16 bf16_t;
typedef __bf16 bf16x8 __attribute__((ext_vector_type(8)));
typedef float f32x4 __attribute__((ext_vector_type(4)));
typedef unsigned short u16;
typedef unsigned short u16x4 __attribute__((ext_vector_type(4)));
typedef unsigned int u32;

#define B_ 4
#define N_ 64
#define P_ 256
#define C_ 384
#define H_ 6
#define D_ 64
#define M_TOTAL 65536
#define NQKV 1152
#define KSTEPS 12                     // 384/32
#define NBLK (H_*B_*N_)               // 1536 = 8 XCDs * 192
#define WKS_U16 10240                 // 20KB per (h,ks): 12 hi frags + 8 lo frags x 1KB
#define WKS_BYTES 20480
// LDS map (u16 offsets):
//   Kh 0..16384  Kl 16384..32768  Vt 32768..49152
//   stage0 49152..59392, stage1 59392..69632        (phase 1)
//   Qb = 49152 + wid*1024 (16 waves, 32KB)          (epilogue, stage dead)
//   Pb = 49152 + wid*640  (20KB)                    (phase 3)
#define FUSED_LDS 139264
#define PB_STRIDE 40
#define SB() __builtin_amdgcn_sched_barrier(0)

#define GLOAD_LDS16(g, l) __builtin_amdgcn_global_load_lds( \
    (const __attribute__((address_space(1))) void*)(g), \
    (__attribute__((address_space(3))) void*)(l), 16, 0, 0)

__device__ __forceinline__ u16 f2b(float f){ return __builtin_bit_cast(u16, (bf16_t)f); }
__device__ __forceinline__ f32x4 mfma(bf16x8 a, bf16x8 b, f32x4 c){
    return __builtin_amdgcn_mfma_f32_16x16x32_bf16(a, b, c, 0, 0, 0);
}

// ---------------------------------------------------------------------------
// prep: (a) packed per-(h,ks) 20KB weight blocks [12 hi | 8 lo] fragments
//       (b) w_proj^T bf16
// ---------------------------------------------------------------------------
__global__ __launch_bounds__(256) void prep_w(
    const float* __restrict__ wqkv, const float* __restrict__ wproj,
    u16* __restrict__ Wpk, u16* __restrict__ wPt)
{
    int i = blockIdx.x * 256 + threadIdx.x;
    const int NSLOT = H_ * KSTEPS * 12 * 64;   // 55296
    if (i < NSLOT) {
        int lane = i & 63;
        int frag = i >> 6;
        int nf = frag % 12;
        int ks = (frag / 12) % KSTEPS;
        int h  = frag / (12 * KSTEPS);
        int part = nf >> 2;                        // 0=Q 1=K 2=V
        int nh   = (nf & 3) * 16 + (lane & 15);
        int col  = part * C_ + h * 64 + nh;
        int k0   = ks * 32 + (lane >> 4) * 8;
        size_t base = (size_t)(h * KSTEPS + ks) * WKS_U16;
        #pragma unroll
        for (int e = 0; e < 8; ++e) {
            float w = wqkv[(size_t)(k0 + e) * NQKV + col];
            bf16_t hi = (bf16_t)w;
            Wpk[base + nf * 512 + lane * 8 + e] = __builtin_bit_cast(u16, hi);
            if (nf < 8)
                Wpk[base + 6144 + nf * 512 + lane * 8 + e] = f2b(w - (float)hi);
        }
    }
    int j = i - NSLOT;
    if (j >= 0 && j < C_ * C_) {
        int k = j / C_, n = j % C_;
        wPt[(size_t)n * C_ + k] = f2b(wproj[j]);
    }
}

// ---------------------------------------------------------------------------
// fused per-(h, b*n) kernel: 1024 threads = 16 waves, wave owns 16 q-rows.
// 4 waves/SIMD for latency hiding; per-wave live set sized to the 128-reg
// budget (S halves to 64 f32). Weights staged via global_load_lds dbuf.
// ---------------------------------------------------------------------------
__global__ __launch_bounds__(1024, 4) void fused_attn(
    const float* __restrict__ x, const u16* __restrict__ Wpk,
    u16* __restrict__ attn)
{
    extern __shared__ u16 sm[];
    u16* Kh = sm;
    u16* Kl = sm + 16384;
    u16* Vt = sm + 32768;

    const int tid  = threadIdx.x;
    const int lane = tid & 63, wid = tid >> 6;
    const int g = lane >> 4, r16 = lane & 15;

    // XCD-chunk swizzle (bijective: 1536 = 8 * 192)
    const int p = blockIdx.x;
    const int logical = (p & 7) * (NBLK / 8) + (p >> 3);
    const int h  = logical % H_;
    const int bn = logical / H_;
    const size_t row0 = (size_t)bn * P_;
    const int m0w = wid * 16;

    // ---------------- phase 1: [Q|K|V](16 rows) = X @ W3head, split bf16 ---
    f32x4 acc[12];
    #pragma unroll
    for (int nf = 0; nf < 12; ++nf) acc[nf] = f32x4{0.f,0.f,0.f,0.f};

    const float* xr0 = x + (row0 + m0w + r16) * C_;
    const char* wbase = (const char*)Wpk + (size_t)h * (KSTEPS * WKS_BYTES);

#define STAGE(ks_, par_) do { \
    const char* _gp = wbase + (size_t)(ks_) * WKS_BYTES; \
    char* _lp = (char*)(sm + 49152 + (par_) * WKS_U16); \
    GLOAD_LDS16(_gp + tid * 16, _lp + tid * 16); \
    if (tid < 256) GLOAD_LDS16(_gp + 16384 + tid * 16, _lp + 16384 + tid * 16); \
} while (0)

    f32x4 xr[2][2];
#define XLOAD(ks_, par_) do { \
    const float* _xp = xr0 + (ks_) * 32 + 8 * g; \
    xr[par_][0] = *(const f32x4*)_xp; xr[par_][1] = *(const f32x4*)(_xp + 4); \
} while (0)

    bf16x8 ah, al;
#define SPLIT_A(par_) do { \
    _Pragma("unroll") \
    for (int e = 0; e < 4; ++e) { \
        bf16_t h0 = (bf16_t)xr[par_][0][e], h1 = (bf16_t)xr[par_][1][e]; \
        ah[e]   = h0; al[e]   = (bf16_t)(xr[par_][0][e] - (float)h0); \
        ah[4+e] = h1; al[4+e] = (bf16_t)(xr[par_][1][e] - (float)h1); \
    } } while (0)

    STAGE(0, 0);
    XLOAD(0, 0);
    __syncthreads();

    #pragma unroll
    for (int ks = 0; ks < KSTEPS; ++ks) {
        const int par = ks & 1, nxt = par ^ 1;
        if (ks < KSTEPS - 1) {
            STAGE(ks + 1, nxt);
            XLOAD(ks + 1, nxt);
        }
        SPLIT_A(par);
        const u16* stg = sm + 49152 + par * WKS_U16;
        #pragma unroll
        for (int nf = 0; nf < 8; ++nf) {    // Q,K: split 3x
            bf16x8 bh = *(const bf16x8*)&stg[nf * 512 + lane * 8];
            bf16x8 bl = *(const bf16x8*)&stg[6144 + nf * 512 + lane * 8];
            acc[nf] = mfma(ah, bh, acc[nf]);
            acc[nf] = mfma(ah, bl, acc[nf]);
            acc[nf] = mfma(al, bh, acc[nf]);
        }
        #pragma unroll
        for (int nf = 8; nf < 12; ++nf) {   // V: plain
            bf16x8 bh = *(const bf16x8*)&stg[nf * 512 + lane * 8];
            acc[nf] = mfma(ah, bh, acc[nf]);
        }
        __syncthreads();   // stage(ks+1) complete + all waves done with stg[par]
    }

    // ---- epilogue: K -> Kh/Kl (split), V -> Vt (transposed), swizzled ----
    #pragma unroll
    for (int f = 0; f < 4; ++f)
    #pragma unroll
    for (int rr = 0; rr < 4; ++rr) {
        int q = m0w + 4 * g + rr;
        int d = f * 16 + r16;
        int ek = q * 64 + (((d >> 3) ^ (q & 7)) << 3) + (d & 7);
        float kv = acc[4 + f][rr];
        bf16_t khi = (bf16_t)kv;
        Kh[ek] = __builtin_bit_cast(u16, khi);
        Kl[ek] = f2b(kv - (float)khi);
        Vt[d * 256 + (((q >> 3) ^ (d & 7)) << 3) + (q & 7)] = f2b(acc[8 + f][rr]);
    }

    // ---- Q bounce (per-wave, stage region is dead after last barrier) ----
    u16* myQb = sm + 49152 + wid * 1024;   // [16][64] swizzled
    bf16x8 aqh[2], aql[2];
    #pragma unroll
    for (int f = 0; f < 4; ++f)
    #pragma unroll
    for (int rr = 0; rr < 4; ++rr) {
        int r = 4 * g + rr;
        int c = f * 16 + r16;
        myQb[r * 64 + (((c >> 3) ^ (r & 7)) << 3) + (c & 7)] = f2b(acc[f][rr]);
    }
    #pragma unroll
    for (int k2 = 0; k2 < 2; ++k2)
        aqh[k2] = *(const bf16x8*)&myQb[r16 * 64 + (((k2 * 4 + g) ^ (r16 & 7)) << 3)];
    SB();   // keep lo-pass writes after hi-pass reads
    #pragma unroll
    for (int f = 0; f < 4; ++f)
    #pragma unroll
    for (int rr = 0; rr < 4; ++rr) {
        int r = 4 * g + rr;
        int c = f * 16 + r16;
        float v = acc[f][rr];
        bf16_t hi = (bf16_t)v;
        myQb[r * 64 + (((c >> 3) ^ (r & 7)) << 3) + (c & 7)] = f2b(v - (float)hi);
    }
    #pragma unroll
    for (int k2 = 0; k2 < 2; ++k2)
        aql[k2] = *(const bf16x8*)&myQb[r16 * 64 + (((k2 * 4 + g) ^ (r16 & 7)) << 3)];

    __syncthreads();   // Kh/Kl/Vt visible block-wide

    // ---------------- phase 2: S = Q K^T (split, 3 MFMA), prefetch 1 nf ----
    f32x4 S[16];
    #pragma unroll
    for (int nf = 0; nf < 16; ++nf) S[nf] = f32x4{0.f,0.f,0.f,0.f};

    bf16x8 khv[2][2], klv[2][2];
    {
        int q = r16;
        #pragma unroll
        for (int k2 = 0; k2 < 2; ++k2) {
            int e = q * 64 + (((k2 * 4 + g) ^ (q & 7)) << 3);
            khv[0][k2] = *(const bf16x8*)&Kh[e];
            klv[0][k2] = *(const bf16x8*)&Kl[e];
        }
    }
    #pragma unroll
    for (int nf = 0; nf < 16; ++nf) {
        const int par = nf & 1, nxt = par ^ 1;
        if (nf < 15) {
            int q = (nf + 1) * 16 + r16;
            #pragma unroll
            for (int k2 = 0; k2 < 2; ++k2) {
                int e = q * 64 + (((k2 * 4 + g) ^ (q & 7)) << 3);
                khv[nxt][k2] = *(const bf16x8*)&Kh[e];
                klv[nxt][k2] = *(const bf16x8*)&Kl[e];
            }
        }
        SB();
        __builtin_amdgcn_s_setprio(1);
        #pragma unroll
        for (int k2 = 0; k2 < 2; ++k2) {
            S[nf] = mfma(aqh[k2], khv[par][k2], S[nf]);
            S[nf] = mfma(aqh[k2], klv[par][k2], S[nf]);
            S[nf] = mfma(aql[k2], khv[par][k2], S[nf]);
        }
        __builtin_amdgcn_s_setprio(0);
        SB();
    }

    // ---------------- softmax (rows lane-spread over 16 lanes) -------------
    {
        float mrow[4] = {-1e30f,-1e30f,-1e30f,-1e30f};
        #pragma unroll
        for (int nf = 0; nf < 16; ++nf)
            #pragma unroll
            for (int rr = 0; rr < 4; ++rr) mrow[rr] = fmaxf(mrow[rr], S[nf][rr]);
        #pragma unroll
        for (int mask = 1; mask < 16; mask <<= 1)
            #pragma unroll
            for (int rr = 0; rr < 4; ++rr) mrow[rr] = fmaxf(mrow[rr], __shfl_xor(mrow[rr], mask, 64));
        float ssum[4] = {0.f,0.f,0.f,0.f};
        #pragma unroll
        for (int nf = 0; nf < 16; ++nf)
            #pragma unroll
            for (int rr = 0; rr < 4; ++rr) {
                float pv = __expf((S[nf][rr] - mrow[rr]) * 64.0f);  // scale = D
                S[nf][rr] = pv;
                ssum[rr] += pv;
            }
        #pragma unroll
        for (int mask = 1; mask < 16; mask <<= 1)
            #pragma unroll
            for (int rr = 0; rr < 4; ++rr) ssum[rr] += __shfl_xor(ssum[rr], mask, 64);
        float inv_[4];
        #pragma unroll
        for (int rr = 0; rr < 4; ++rr) inv_[rr] = 1.0f / ssum[rr];
        #pragma unroll
        for (int nf = 0; nf < 16; ++nf)       // fold 1/sum into P now
            #pragma unroll
            for (int rr = 0; rr < 4; ++rr) S[nf][rr] *= inv_[rr];
    }

    // ---------------- phase 3: O = P V (per-wave bounce, stride 40) --------
    f32x4 O[4];
    #pragma unroll
    for (int f = 0; f < 4; ++f) O[f] = f32x4{0.f,0.f,0.f,0.f};

    u16* pb = sm + 49152 + wid * 640;        // [16][PB_STRIDE]
    #pragma unroll
    for (int t = 0; t < 8; ++t) {
        bf16x8 bv[4];
        #pragma unroll
        for (int f = 0; f < 4; ++f) {
            int d = f * 16 + r16;
            bv[f] = *(const bf16x8*)&Vt[d * 256 + ((((t * 32 + 8 * g) >> 3) ^ (d & 7)) << 3)];
        }
        #pragma unroll
        for (int tt = 0; tt < 2; ++tt) {
            int nf = 2 * t + tt;
            #pragma unroll
            for (int rr = 0; rr < 4; ++rr)
                pb[(4 * g + rr) * PB_STRIDE + tt * 16 + r16] = f2b(S[nf][rr]);
        }
        bf16x8 ap = *(const bf16x8*)&pb[r16 * PB_STRIDE + 8 * g];
        __builtin_amdgcn_s_setprio(1);
        #pragma unroll
        for (int f = 0; f < 4; ++f) O[f] = mfma(ap, bv[f], O[f]);
        __builtin_amdgcn_s_setprio(0);
    }

    #pragma unroll
    for (int f = 0; f < 4; ++f)
    #pragma unroll
    for (int rr = 0; rr < 4; ++rr)
        attn[(row0 + m0w + 4 * g + rr) * C_ + h * 64 + f * 16 + r16] = f2b(O[f][rr]);
}

// ---------------------------------------------------------------------------
// proj: attn(65536x384 bf16) @ w_proj(384x384) + bias -> f32 out.
// ---------------------------------------------------------------------------
__global__ __launch_bounds__(256, 2) void proj_kernel(
    const u16* __restrict__ attn, const u16* __restrict__ wPt,
    const float* __restrict__ bias, float* __restrict__ out)
{
    __shared__ alignas(16) u16 As[128*32];
    __shared__ alignas(16) u16 Bs[128*32];

    const int tid = threadIdx.x;
    const int lane = tid & 63, wid = tid >> 6;
    const int wr = wid >> 1, wc = wid & 1;
    const int g = lane >> 4, r16 = lane & 15;
    const int m0 = blockIdx.x * 128;
    const int n0 = blockIdx.y * 128;

    f32x4 acc[4][4];
    for (int i = 0; i < 4; i++) for (int j = 0; j < 4; j++) acc[i][j] = f32x4{0.f,0.f,0.f,0.f};

    for (int kt = 0; kt < C_; kt += 32) {
        for (int r = 0; r < 4; ++r) {
            int i = tid + 256*r;
            int mm = i >> 3;
            int kk = (i & 7) << 2;
            u16x4 v = *(const u16x4*)&attn[(size_t)(m0+mm)*C_ + kt + kk];
            int e = mm*32 + (((kk>>3) ^ ((mm>>1)&3))<<3) + (kk&7);
            *(u16x4*)&As[e] = v;
        }
        for (int r = 0; r < 4; ++r) {
            int i = tid + 256*r;
            int nn = i >> 3;
            int kk = (i & 7) << 2;
            u16x4 v = *(const u16x4*)&wPt[(size_t)(n0+nn)*C_ + kt + kk];
            int e = nn*32 + (((kk>>3) ^ ((nn>>1)&3))<<3) + (kk&7);
            *(u16x4*)&Bs[e] = v;
        }
        __syncthreads();

        bf16x8 a[4], b[4];
        for (int i = 0; i < 4; i++) {
            int row = wr*64 + i*16 + r16;
            a[i] = *(const bf16x8*)&As[row*32 + ((g ^ ((row>>1)&3))<<3)];
        }
        for (int j = 0; j < 4; j++) {
            int n = wc*64 + j*16 + r16;
            b[j] = *(const bf16x8*)&Bs[n*32 + ((g ^ ((n>>1)&3))<<3)];
        }
        for (int i = 0; i < 4; i++) for (int j = 0; j < 4; j++)
            acc[i][j] = mfma(a[i], b[j], acc[i][j]);
        __syncthreads();
    }

    for (int i = 0; i < 4; i++) for (int j = 0; j < 4; j++) for (int rr = 0; rr < 4; rr++) {
        size_t row = m0 + wr*64 + i*16 + g*4 + rr;
        int col = n0 + wc*64 + j*16 + r16;
        out[row*C_ + col] = acc[i][j][rr] + bias[col];
    }
}

// ---------------------------------------------------------------------------
extern "C" void kernel_launch(void* const* d_in, const int* in_sizes, int n_in,
                              void* d_out, int out_size, void* d_ws, size_t ws_size,
                              hipStream_t stream)
{
    const float* x      = (const float*)d_in[0];
    const float* w_qkv  = (const float*)d_in[1];
    const float* w_proj = (const float*)d_in[2];
    const float* b_proj = (const float*)d_in[3];
    float* out = (float*)d_out;

    u16* ws = (u16*)d_ws;
    u16* attnb = ws;                                  // 65536*384 u16 = 50 MB
    size_t off = (size_t)M_TOTAL * C_;
    u16* Wpk = ws + off; off += (size_t)H_ * KSTEPS * WKS_U16;
    u16* wPt = ws + off; off += (size_t)C_ * C_;

    hipFuncSetAttribute((const void*)fused_attn,
                        hipFuncAttributeMaxDynamicSharedMemorySize, FUSED_LDS);

    int prep_n = H_ * KSTEPS * 12 * 64 + C_ * C_;
    prep_w<<<dim3((prep_n + 255) / 256), 256, 0, stream>>>(w_qkv, w_proj, Wpk, wPt);
    fused_attn<<<dim3(NBLK), 1024, FUSED_LDS, stream>>>(x, Wpk, attnb);
    proj_kernel<<<dim3(M_TOTAL / 128, C_ / 128), 256, 0, stream>>>(attnb, wPt, b_proj, out);
}